// Round 16
// baseline (722.030 us; speedup 1.0000x reference)
//
#include <hip/hip_runtime.h>
#include <hip/hip_bf16.h>
#include <math.h>

#define NHEADS 8
#define L2E 1.44269504f

typedef __attribute__((ext_vector_type(8))) __bf16 bfrag;
typedef __attribute__((ext_vector_type(4))) float f32x4;
typedef __attribute__((ext_vector_type(8))) unsigned short u16x8;

static __device__ __forceinline__ unsigned short f2bf(float f) {
  unsigned u = __float_as_uint(f);
  unsigned r = (u + 0x7fffu + ((u >> 16) & 1u)) >> 16;
  return (unsigned short)r;
}

static __device__ __forceinline__ void gload_lds16(const void* g, void* l) {
  __builtin_amdgcn_global_load_lds(
      (const __attribute__((address_space(1))) unsigned int*)g,
      (__attribute__((address_space(3))) unsigned int*)l, 16, 0, 0);
}

static __device__ __forceinline__ float block_reduce_sum(float v, float* red) {
  int t = threadIdx.x;
  red[t] = v; __syncthreads();
  for (int s = 128; s > 0; s >>= 1) {
    if (t < s) red[t] += red[t + s];
    __syncthreads();
  }
  float r = red[0];
  __syncthreads();
  return r;
}

// ---------------- sigmoid table (bf16, padded to Kp) + row sums ----------------
__global__ __launch_bounds__(256) void sig_kernel(
    const float* __restrict__ Wp, unsigned short* __restrict__ Sgb,
    float* __restrict__ Ssum, int Kd, int Kp)
{
  __shared__ float red[256];
  int row = blockIdx.x;
  float s = 0.f;
  for (int k = threadIdx.x; k < Kp; k += 256) {
    float v = 0.f;
    if (k < Kd) {
      v = 1.f / (1.f + __expf(-Wp[(size_t)row * Kd + k]));
      s += v;
    }
    Sgb[(size_t)row * Kp + k] = f2bf(v);
  }
  float tot = block_reduce_sum(s, red);
  if (threadIdx.x == 0) Ssum[row] = tot;
}

// ---------------- fused transpose+convert for all weights ----------------
struct TDesc { const float* src; unsigned short* dst; int K, N, Kp, tilesX, blk0; };
struct TPack { TDesc d[16]; };

__global__ __launch_bounds__(256) void tconv_all_kernel(TPack P) {
  __shared__ float t[32][33];
  int bid = blockIdx.x;
  int di = 0;
  #pragma unroll
  for (int k = 1; k < 16; ++k) if (bid >= P.d[k].blk0) di = k;
  const float* src = P.d[di].src;
  unsigned short* dst = P.d[di].dst;
  int K = P.d[di].K, N = P.d[di].N, Kp = P.d[di].Kp, tilesX = P.d[di].tilesX;
  int local = bid - P.d[di].blk0;
  int bn = (local % tilesX) * 32;
  int bk = (local / tilesX) * 32;
  int tid = threadIdx.x;
  int tx = tid & 31, ty = tid >> 5;
  #pragma unroll
  for (int u = 0; u < 4; ++u) {
    int k = bk + ty + u * 8, n = bn + tx;
    t[ty + u * 8][tx] = (k < K && n < N) ? src[(size_t)k * N + n] : 0.f;
  }
  __syncthreads();
  #pragma unroll
  for (int u = 0; u < 4; ++u) {
    int n = bn + ty + u * 8, kk = bk + tx;
    if (n < N && kk < Kp)
      dst[(size_t)n * Kp + kk] = f2bf(t[tx][ty + u * 8]);
  }
}

// ---------------- MFMA bf16 GEMM: C = epi(A @ Bt^T + bias) ----------------
// Tiles: (BM,TN) in {(128,128),(128,64),(64,64)}. 4 waves = 2x2.
template<int BM, int TN, int EPI, bool WF32, bool WBF, bool WTR>
__global__ __launch_bounds__(256) void mgemm_kernel(
    const unsigned short* __restrict__ A, const unsigned short* __restrict__ Bt,
    const float* __restrict__ bias, float* __restrict__ C,
    unsigned short* __restrict__ Cb, unsigned short* __restrict__ Ct,
    int M, int N, int K, const float* __restrict__ divv,
    const float* __restrict__ bias2, int Nk)
{
  constexpr int NI = BM / 32, NJ = TN / 32;
  constexpr int WR = BM / 2, WC = TN / 2;
  constexpr bool SPLIT = WBF && WTR;
  __shared__ __align__(16) unsigned short Als[BM * 32];
  __shared__ __align__(16) unsigned short Bls[TN * 32];
  const int tid = threadIdx.x;
  const int lane = tid & 63, w = tid >> 6;
  const int wm = w >> 1, wn = w & 1;
  const int brow = blockIdx.y * BM, bcol = blockIdx.x * TN;

  f32x4 acc[NI][NJ] = {};

  for (int k0 = 0; k0 < K; k0 += 32) {
    if constexpr (TN == 128) {
      #pragma unroll
      for (int q = 0; q < 2; ++q) {
        int s = w * 128 + q * 64 + lane;
        int r = s >> 2, g = s & 3;
        int gs = g ^ (r & 3);
        int gc = bcol + r; if (gc > N - 1) gc = N - 1;
        gload_lds16(Bt + (size_t)gc * K + k0 + gs * 8,
                    (char*)Bls + (w * 2048 + q * 1024));
      }
    } else {
      int s = tid;
      int r = s >> 2, g = s & 3;
      int gs = g ^ (r & 3);
      int gc = bcol + r; if (gc > N - 1) gc = N - 1;
      gload_lds16(Bt + (size_t)gc * K + k0 + gs * 8,
                  (char*)Bls + w * 1024);
    }
    if constexpr (BM == 128) {
      #pragma unroll
      for (int q = 0; q < 2; ++q) {
        int s = w * 128 + q * 64 + lane;
        int r = s >> 2, g = s & 3;
        int gs = g ^ (r & 3);
        int gr = brow + r; if (gr > M - 1) gr = M - 1;
        gload_lds16(A + (size_t)gr * K + k0 + gs * 8,
                    (char*)Als + (w * 2048 + q * 1024));
      }
    } else {
      int s = tid;
      int r = s >> 2, g = s & 3;
      int gs = g ^ (r & 3);
      int gr = brow + r; if (gr > M - 1) gr = M - 1;
      gload_lds16(A + (size_t)gr * K + k0 + gs * 8,
                  (char*)Als + w * 1024);
    }
    __syncthreads();

    bfrag av[NI], bv[NJ];
    #pragma unroll
    for (int f = 0; f < NI; ++f) {
      int rA = wm * WR + f * 16 + (lane & 15);
      av[f] = *(const bfrag*)((const char*)Als + rA * 64 + ((((lane >> 4) ^ (rA & 3))) << 4));
    }
    #pragma unroll
    for (int f = 0; f < NJ; ++f) {
      int rB = wn * WC + f * 16 + (lane & 15);
      bv[f] = *(const bfrag*)((const char*)Bls + rB * 64 + ((((lane >> 4) ^ (rB & 3))) << 4));
    }
    #pragma unroll
    for (int i = 0; i < NI; ++i)
      #pragma unroll
      for (int j = 0; j < NJ; ++j)
        acc[i][j] = __builtin_amdgcn_mfma_f32_16x16x32_bf16(av[i], bv[j], acc[i][j], 0, 0, 0);
    __syncthreads();
  }

  #pragma unroll
  for (int i = 0; i < NI; ++i) {
    int gr0 = brow + wm * WR + i * 16 + (lane >> 4) * 4;
    #pragma unroll
    for (int j = 0; j < NJ; ++j) {
      int gc = bcol + wn * WC + j * 16 + (lane & 15);
      float bsv;
      if (SPLIT) bsv = (gc < Nk) ? bias[gc] : bias2[gc - Nk];
      else       bsv = bias ? bias[gc] : 0.f;
      float vv[4];
      #pragma unroll
      for (int q = 0; q < 4; ++q) {
        int gr = gr0 + q;
        float v = acc[i][j][q] + bsv;
        if (EPI >= 1) v = fmaxf(v, 0.f);
        if (EPI == 2) v = (gr < M) ? v / divv[gr] : v;
        vv[q] = v;
      }
      if (SPLIT) {
        if (gc < Nk) {
          #pragma unroll
          for (int q = 0; q < 4; ++q) {
            int gr = gr0 + q;
            if (gr < M) Cb[(size_t)gr * Nk + gc] = f2bf(vv[q]);
          }
        } else {
          ushort4 h4 = { f2bf(vv[0]), f2bf(vv[1]), f2bf(vv[2]), f2bf(vv[3]) };
          *(ushort4*)(Ct + (size_t)(gc - Nk) * M + gr0) = h4;
        }
      } else {
        #pragma unroll
        for (int q = 0; q < 4; ++q) {
          int gr = gr0 + q;
          if (gr >= M) continue;
          if (WF32) C[(size_t)gr * N + gc] = vv[q];
          if (WBF)  Cb[(size_t)gr * N + gc] = f2bf(vv[q]);
        }
        if (WTR) {
          ushort4 h4 = { f2bf(vv[0]), f2bf(vv[1]), f2bf(vv[2]), f2bf(vv[3]) };
          *(ushort4*)(Ct + (size_t)gc * M + gr0) = h4;
        }
      }
    }
  }
}

// ---------------- embedding gather ----------------
__global__ __launch_bounds__(256) void gather_kernel(
    const int* __restrict__ p_data, const int* __restrict__ pa_data,
    const float* __restrict__ E, const float* __restrict__ diff_W,
    float* __restrict__ qemb, unsigned short* __restrict__ qembb,
    float* __restrict__ qaemb, unsigned short* __restrict__ qaembb)
{
  int idx = blockIdx.x * 256 + threadIdx.x;
  if (idx >= 8192 * 512) return;
  int row = idx >> 9, c = idx & 511;
  int p = p_data[row];
  float pid = diff_W[p];
  if (c < 256) {
    float v = E[(size_t)p * 256 + c] + pid;
    qemb[(size_t)row * 256 + c] = v;
    qembb[(size_t)row * 256 + c] = f2bf(v);
  }
  int pa = pa_data[row];
  int ppos = (pa > 4096) ? pa - 4096 : 0;
  int pneg = (pa <= 4096) ? pa : 0;
  float v = (c < 256) ? E[(size_t)ppos * 256 + c] : E[(size_t)pneg * 256 + (c - 256)];
  v += pid;
  qaemb[(size_t)row * 512 + c] = v;
  qaembb[(size_t)row * 512 + c] = f2bf(v);
}

// ---------------- c_reg ----------------
__global__ __launch_bounds__(256) void creg_kernel(
    const int* __restrict__ p_data, const float* __restrict__ dW,
    float* __restrict__ out)
{
  __shared__ float red[256];
  float s = 0.f;
  for (int i = threadIdx.x; i < 8192; i += 256) {
    float v = dW[p_data[i]];
    s += v * v;
  }
  float tot = block_reduce_sum(s, red);
  if (threadIdx.x == 0) out[0] = tot * 1e-5f;
}

// ---------------- MFMA distance-decay attention v15 ----------------
// As v14 (3-pass streaming softmax), plus V-fragment prefetch issued right after
// QK^T and pinned with sched_barrier(0) so HBM/L2 latency hides under softmax.
template<int DK, int DV, int MASKK, int ZP>
__global__ __launch_bounds__(512, 4) void attnD_kernel(
    const unsigned short* __restrict__ QKb, const unsigned short* __restrict__ Vt,
    const float* __restrict__ gamp, unsigned short* __restrict__ O,
    int S, int MT)
{
  constexpr int RS = 1156;
  constexpr int NPAR = (DV == 64) ? 2 : 4;
  constexpr int NFIN = (DV == 64) ? 4 : 2;
  constexpr int NP   = (DV == 32) ? 6 : 4;
  constexpr int MAXPF = (DV == 64) ? 8 : 4;     // max PV iterations per wave
  const int DMK = NHEADS * DK, DMV = NHEADS * DV;
  const int id = blockIdx.x + blockIdx.y * 64;
  const int W = (id & 7) * 512 + (id >> 3);     // XCD-chunked bijection (4096 blocks)
  const int ib = 63 - (W & 63);                 // descending-NK order
  const int bh = W >> 6;
  const int i0 = ib * 16;
  const int b = bh >> 3, h = bh & 7;
  const int tid = threadIdx.x;
  const int lane = tid & 63, w = tid >> 6;
  const size_t rowbase = (size_t)b * S;

  __shared__ __align__(16) float sc[16 * RS];
  __shared__ float wrow[16];

  const int jmaxBlk = MASKK ? (i0 + 15) : (i0 + 14);
  const int NK = (jmaxBlk / 64 + 1) * 64;
  const int NKp = (NK + 255) & ~255;            // 256..1024
  const int CD = NKp >> 5;                      // 8,16,24,32 elems/lane

  const int qr = lane & 15;
  const int ko8 = (lane >> 4) * 8;
  const float rscale = rsqrtf((float)DK) * L2E;

  // PV role constants (needed early for prefetch)
  const int dblk = (DV == 64) ? (w & 3) : (w & 1);
  const int par  = (DV == 64) ? (w >> 2) : (w >> 1);
  const int dcol = h * DV + dblk * 16 + (lane & 15);
  const unsigned short* vrow = Vt + (size_t)dcol * MT + rowbase;
  bfrag vpre[2 * MAXPF];

  bfrag qf[DK / 32];
  #pragma unroll
  for (int ks = 0; ks < DK / 32; ++ks)
    qf[ks] = *(const bfrag*)(QKb + (rowbase + i0 + qr) * DMK + h * DK + ks * 32 + ko8);

  // ---- QK^T (rscale*L2E folded into scatter) ----
  for (int t0 = 0; t0 < NK; t0 += 128) {
    int tt = t0 + (w >> 2) * 64;
    if (tt < NK) {
      int jb = tt + (w & 3) * 16 + qr;
      bfrag kf[DK / 32];
      #pragma unroll
      for (int ks = 0; ks < DK / 32; ++ks)
        kf[ks] = *(const bfrag*)(QKb + (rowbase + jb) * DMK + h * DK + ks * 32 + ko8);
      f32x4 accs = {};
      __builtin_amdgcn_s_setprio(1);
      #pragma unroll
      for (int ks = 0; ks < DK / 32; ++ks)
        accs = __builtin_amdgcn_mfma_f32_16x16x32_bf16(qf[ks], kf[ks], accs, 0, 0, 0);
      __builtin_amdgcn_s_setprio(0);
      int ja = jb + 4 * (jb >> 5);
      int r0 = (lane >> 4) * 4;
      #pragma unroll
      for (int q = 0; q < 4; ++q)
        sc[(r0 + q) * RS + ja] = accs[q] * rscale;
    }
  }

  // ---- issue V prefetch NOW; sched_barrier pins the issues above the barrier ----
  #pragma unroll
  for (int it = 0; it < MAXPF; ++it) {
    int t0 = (par + it * NPAR) * 64;
    int t0c = (t0 < NK) ? t0 : 0;
    #pragma unroll
    for (int ks = 0; ks < 2; ++ks)
      vpre[it * 2 + ks] = *(const bfrag*)(vrow + t0c + ks * 32 + ko8);
  }
  __builtin_amdgcn_sched_barrier(0);
  __syncthreads();

  // ---- streaming softmax (exp2 domain), 3 passes ----
  {
    const int g = tid >> 5, l = tid & 31;
    const int i = i0 + g;
    const int jmax = MASKK ? i : i - 1;
    const int jb0 = CD * l;
    const int CD4 = CD >> 2;
    float* rowF = sc + g * RS;

    // P1: max
    float m1 = -1e30f;
    for (int c = 0; c < CD4; ++c) {
      int j = jb0 + 4 * c;
      f32x4 v = *(const f32x4*)(rowF + j + 4 * (j >> 5));
      #pragma unroll
      for (int k = 0; k < 4; ++k)
        m1 = fmaxf(m1, (j + k <= jmax) ? v[k] : -1e30f);
    }
    #pragma unroll
    for (int o = 16; o > 0; o >>= 1) m1 = fmaxf(m1, __shfl_xor(m1, o, 32));

    // P2: lane-local sum of exp2
    float lloc = 0.f;
    for (int c = 0; c < CD4; ++c) {
      int j = jb0 + 4 * c;
      f32x4 v = *(const f32x4*)(rowF + j + 4 * (j >> 5));
      #pragma unroll
      for (int k = 0; k < 4; ++k)
        lloc += (j + k <= jmax) ? __builtin_amdgcn_exp2f(v[k] - m1) : 0.f;
    }
    float l1 = lloc;
    #pragma unroll
    for (int o = 16; o > 0; o >>= 1) l1 += __shfl_xor(l1, o, 32);

    float scn = lloc;
    #pragma unroll
    for (int o = 1; o < 32; o <<= 1) {
      float u = __shfl_up(scn, o, 32);
      if (l >= o) scn += u;
    }
    float cum = scn - lloc;

    float gv = gamp[h];
    float sp = fmaxf(gv, 0.f) + log1pf(__expf(-fabsf(gv)));
    float gmr = -sp * L2E * rsqrtf(l1);
    float mS = fmaxf(m1, 0.f);     // safe upper bound on p' = s*eff (eff <= 1)

    // P3: cum/effect + final exp2 + bf16 planes, all in one pass
    float l2 = 0.f;
    for (int c = 0; c < CD4; c += 2) {
      int jo = jb0 + 4 * c;
      char* base = (char*)(rowF + jo + 4 * (jo >> 5));
      f32x4 a = *(const f32x4*)base;
      f32x4 bq = *(const f32x4*)(base + 16);
      u16x8 hi8, lo8;
      #pragma unroll
      for (int e = 0; e < 8; ++e) {
        int jj = jo + e;
        float sv = (e < 4) ? a[e] : bq[e - 4];
        bool ok = jj <= jmax;
        float e1 = ok ? __builtin_amdgcn_exp2f(sv - m1) : 0.f;
        cum += e1;
        float rem = fmaxf(l1 - cum, 0.f);
        float dsq = sqrtf(rem * fabsf((float)(i - jj)));
        float eff = fmaxf(__builtin_amdgcn_exp2f(gmr * dsq), 1e-5f);
        float ev = ok ? __builtin_amdgcn_exp2f(sv * eff - mS) : 0.f;
        l2 += ev;
        __bf16 hb = (__bf16)ev;
        hi8[e] = __builtin_bit_cast(unsigned short, hb);
        lo8[e] = __builtin_bit_cast(unsigned short, (__bf16)(ev - (float)hb));
      }
      *(u16x8*)base = hi8;
      *(u16x8*)(base + 16) = lo8;
    }
    #pragma unroll
    for (int o = 16; o > 0; o >>= 1) l2 += __shfl_xor(l2, o, 32);
    bool validrow = (jmax >= 0) && !(ZP && i == 0);
    float wgt = validrow ? (1.f / l2) : 0.f;
    if (l == 0) wrow[g] = wgt;
  }
  __syncthreads();

  // ---- PV: wave owns (d-block, tile-parity); planes + prefetched V + MFMA ----
  f32x4 acco = {};
  const float* rowF = sc + qr * RS;
  __builtin_amdgcn_s_setprio(1);
  #pragma unroll
  for (int it = 0; it < MAXPF; ++it) {
    int t0 = (par + it * NPAR) * 64;
    if (t0 < NK) {
      #pragma unroll
      for (int ks = 0; ks < 2; ++ks) {
        int jo = t0 + ks * 32 + ko8;
        const char* base = (const char*)(rowF + jo + 4 * (jo >> 5));
        bfrag ph = *(const bfrag*)base;
        bfrag pl = *(const bfrag*)(base + 16);
        bfrag vf = vpre[it * 2 + ks];
        acco = __builtin_amdgcn_mfma_f32_16x16x32_bf16(pl, vf, acco, 0, 0, 0);
        acco = __builtin_amdgcn_mfma_f32_16x16x32_bf16(ph, vf, acco, 0, 0, 0);
      }
    }
  }
  __builtin_amdgcn_s_setprio(0);
  __syncthreads();                 // all plane reads complete; sc reusable

  float* redA = sc;                // alias partial-reduce buffer into sc
  if (w >= NFIN) {
    int slot = w - NFIN;
    #pragma unroll
    for (int q = 0; q < 4; ++q)
      redA[slot * 272 + ((lane >> 4) * 4 + q) * 17 + (lane & 15)] = acco[q];
  }
  __syncthreads();
  if (w < NFIN) {
    for (int pp = w; pp < NP; pp += NFIN) {
      #pragma unroll
      for (int q = 0; q < 4; ++q)
        acco[q] += redA[pp * 272 + ((lane >> 4) * 4 + q) * 17 + (lane & 15)];
    }
    int r0 = (lane >> 4) * 4;
    #pragma unroll
    for (int q = 0; q < 4; ++q) {
      float wv = wrow[r0 + q];
      O[(rowbase + i0 + r0 + q) * DMV + dcol] = f2bf(acco[q] * wv);
    }
  }
}

// ---------------- LayerNorm v4: one row per wave, float4 loads ----------------
template<int D, bool WF, bool WB>
__global__ __launch_bounds__(256) void ln4_kernel(
    const float* __restrict__ X, const float* __restrict__ R,
    const float* __restrict__ g, const float* __restrict__ be,
    float* __restrict__ Y, unsigned short* __restrict__ Yb)
{
  constexpr int NC = D / 256;
  int row = blockIdx.x * 4 + (threadIdx.x >> 6);
  int lane = threadIdx.x & 63;
  const float* x = X + (size_t)row * D;
  f32x4 xv[NC];
  float s = 0.f;
  #pragma unroll
  for (int c = 0; c < NC; ++c) {
    xv[c] = *(const f32x4*)(x + c * 256 + lane * 4);
    if (R) {
      f32x4 rv = *(const f32x4*)(R + (size_t)row * D + c * 256 + lane * 4);
      #pragma unroll
      for (int k = 0; k < 4; ++k) xv[c][k] += rv[k];
    }
    #pragma unroll
    for (int k = 0; k < 4; ++k) s += xv[c][k];
  }
  #pragma unroll
  for (int o = 32; o > 0; o >>= 1) s += __shfl_xor(s, o, 64);
  float mean = s / (float)D;
  float vs = 0.f;
  #pragma unroll
  for (int c = 0; c < NC; ++c)
    #pragma unroll
    for (int k = 0; k < 4; ++k) { float d = xv[c][k] - mean; vs += d * d; }
  #pragma unroll
  for (int o = 32; o > 0; o >>= 1) vs += __shfl_xor(vs, o, 64);
  float rstd = rsqrtf(vs / (float)D + 1e-5f);
  #pragma unroll
  for (int c = 0; c < NC; ++c) {
    f32x4 gv = *(const f32x4*)(g + c * 256 + lane * 4);
    f32x4 bv = *(const f32x4*)(be + c * 256 + lane * 4);
    f32x4 ov;
    #pragma unroll
    for (int k = 0; k < 4; ++k) ov[k] = gv[k] * (xv[c][k] - mean) * rstd + bv[k];
    if (WF) *(f32x4*)(Y + (size_t)row * D + c * 256 + lane * 4) = ov;
    if (WB) {
      ushort4 h4 = { f2bf(ov[0]), f2bf(ov[1]), f2bf(ov[2]), f2bf(ov[3]) };
      *(ushort4*)(Yb + (size_t)row * D + c * 256 + lane * 4) = h4;
    }
  }
}

// ---------------- fused concat + LN (D=512) ----------------
__global__ __launch_bounds__(256) void lnc_kernel(
    const float* __restrict__ Xh, const float* __restrict__ Qe,
    const float* __restrict__ g, const float* __restrict__ be,
    unsigned short* __restrict__ Yb)
{
  int row = blockIdx.x * 4 + (threadIdx.x >> 6);
  int lane = threadIdx.x & 63;
  f32x4 xv[2];
  xv[0] = *(const f32x4*)(Xh + (size_t)row * 256 + lane * 4);
  xv[1] = *(const f32x4*)(Qe + (size_t)row * 256 + lane * 4);
  float s = 0.f;
  #pragma unroll
  for (int c = 0; c < 2; ++c)
    #pragma unroll
    for (int k = 0; k < 4; ++k) s += xv[c][k];
  #pragma unroll
  for (int o = 32; o > 0; o >>= 1) s += __shfl_xor(s, o, 64);
  float mean = s / 512.f;
  float vs = 0.f;
  #pragma unroll
  for (int c = 0; c < 2; ++c)
    #pragma unroll
    for (int k = 0; k < 4; ++k) { float d = xv[c][k] - mean; vs += d * d; }
  #pragma unroll
  for (int o = 32; o > 0; o >>= 1) vs += __shfl_xor(vs, o, 64);
  float rstd = rsqrtf(vs / 512.f + 1e-5f);
  #pragma unroll
  for (int c = 0; c < 2; ++c) {
    f32x4 gv = *(const f32x4*)(g + c * 256 + lane * 4);
    f32x4 bv = *(const f32x4*)(be + c * 256 + lane * 4);
    ushort4 h4;
    #pragma unroll
    for (int k = 0; k < 4; ++k) {
      float ov = gv[k] * (xv[c][k] - mean) * rstd + bv[k];
      ((unsigned short*)&h4)[k] = f2bf(ov);
    }
    *(ushort4*)(Yb + (size_t)row * 512 + c * 256 + lane * 4) = h4;
  }
}

// ---------------- fused LN(D=256) + dot ----------------
__global__ __launch_bounds__(256) void lndot_kernel(
    const float* __restrict__ X, const float* __restrict__ g,
    const float* __restrict__ be, const float* __restrict__ w3,
    const float* __restrict__ b3, float* __restrict__ out)
{
  int row = blockIdx.x * 4 + (threadIdx.x >> 6);
  int lane = threadIdx.x & 63;
  f32x4 v = *(const f32x4*)(X + (size_t)row * 256 + lane * 4);
  float s = v[0] + v[1] + v[2] + v[3];
  #pragma unroll
  for (int o = 32; o > 0; o >>= 1) s += __shfl_xor(s, o, 64);
  float mean = s / 256.f;
  float vs = 0.f;
  #pragma unroll
  for (int k = 0; k < 4; ++k) { float d = v[k] - mean; vs += d * d; }
  #pragma unroll
  for (int o = 32; o > 0; o >>= 1) vs += __shfl_xor(vs, o, 64);
  float rstd = rsqrtf(vs / 256.f + 1e-5f);
  f32x4 gv = *(const f32x4*)(g + lane * 4);
  f32x4 bv = *(const f32x4*)(be + lane * 4);
  f32x4 wv = *(const f32x4*)(w3 + lane * 4);
  float d = 0.f;
  #pragma unroll
  for (int k = 0; k < 4; ++k)
    d += (gv[k] * (v[k] - mean) * rstd + bv[k]) * wv[k];
  #pragma unroll
  for (int o = 32; o > 0; o >>= 1) d += __shfl_xor(d, o, 64);
  if (lane == 0) out[row] = d + b3[0];
}

// ---------------- launch ----------------
extern "C" void kernel_launch(void* const* d_in, const int* in_sizes, int n_in,
                              void* d_out, int out_size, void* d_ws, size_t ws_size,
                              hipStream_t stream) {
  const int* p_data  = (const int*)d_in[0];
  const int* pa_data = (const int*)d_in[1];
  const float* pemb_W = (const float*)d_in[3];
  const float* diff_W = (const float*)d_in[4];
  const float* qemb_W = (const float*)d_in[5];
  const float* qemb_b = (const float*)d_in[6];
  const float* y_kW = (const float*)d_in[7];   const float* y_kb = (const float*)d_in[8];
  const float* y_vW = (const float*)d_in[9];   const float* y_vb = (const float*)d_in[10];
  const float* y_oW = (const float*)d_in[11];  const float* y_ob = (const float*)d_in[12];
  const float* y_gam = (const float*)d_in[13];
  const float* y_ln1g = (const float*)d_in[14]; const float* y_ln1b = (const float*)d_in[15];
  const float* y_f1W = (const float*)d_in[16]; const float* y_f1b = (const float*)d_in[17];
  const float* y_f2W = (const float*)d_in[18]; const float* y_f2b = (const float*)d_in[19];
  const float* y_ln2g = (const float*)d_in[20]; const float* y_ln2b = (const float*)d_in[21];
  const float* x_kW = (const float*)d_in[22];  const float* x_kb = (const float*)d_in[23];
  const float* x_vW = (const float*)d_in[24];  const float* x_vb = (const float*)d_in[25];
  const float* x_oW = (const float*)d_in[26];  const float* x_ob = (const float*)d_in[27];
  const float* x_gam = (const float*)d_in[28];
  const float* x_ln1g = (const float*)d_in[29]; const float* x_ln1b = (const float*)d_in[30];
  const float* h_kW = (const float*)d_in[31];  const float* h_kb = (const float*)d_in[32];
  const float* h_vW = (const float*)d_in[33];  const float* h_vb = (const float*)d_in[34];
  const float* h_oW = (const float*)d_in[35];  const float* h_ob = (const float*)d_in[36];
  const float* h_gam = (const float*)d_in[37];
  const float* h_ln1g = (const float*)d_in[38]; const float* h_ln1b = (const float*)d_in[39];
  const float* h_f1W = (const float*)d_in[40]; const float* h_f1b = (const float*)d_in[41];
  const float* h_f2W = (const float*)d_in[42]; const float* h_f2b = (const float*)d_in[43];
  const float* h_ln2g = (const float*)d_in[44]; const float* h_ln2b = (const float*)d_in[45];
  const float* oln1g = (const float*)d_in[46]; const float* oln1b = (const float*)d_in[47];
  const float* o1W = (const float*)d_in[48];   const float* o1b = (const float*)d_in[49];
  const float* oln2g = (const float*)d_in[50]; const float* oln2b = (const float*)d_in[51];
  const float* o2W = (const float*)d_in[52];   const float* o2b = (const float*)d_in[53];
  const float* oln3g = (const float*)d_in[54]; const float* oln3b = (const float*)d_in[55];
  const float* o3W = (const float*)d_in[56];   const float* o3b = (const float*)d_in[57];

  float* out_f = (float*)d_out;

  const int B = 8, S = 1024, M = B * S;
  const int R = 4097, KQ = 1025, KQP = 1056;

  float* ws = (float*)d_ws;
  size_t off = 0;
  auto alloc = [&](size_t nfloats) { size_t o = off; off += (nfloats + 255) & ~(size_t)255; return o; };
  auto allocs = [&](size_t nshorts) { return alloc((nshorts + 1) / 2); };

  size_t oE    = alloc((size_t)R * 256);
  size_t oSIGb = allocs((size_t)R * KQP);
  size_t oSSUM = alloc(R);
  size_t oQE   = alloc((size_t)M * 256);
  size_t oQEb  = allocs((size_t)M * 256);
  size_t oQA   = alloc((size_t)M * 512);
  size_t oQAb  = allocs((size_t)M * 512);
  size_t oYOb  = allocs((size_t)M * 512);
  size_t oXO   = alloc((size_t)M * 256);
  size_t oXOb  = allocs((size_t)M * 256);
  size_t oHO   = alloc((size_t)M * 256);
  size_t oS0   = alloc((size_t)M * 512);   // FFb arena (S0+S1)
  size_t oS1   = alloc((size_t)M * 512);
  size_t oS2b  = allocs((size_t)M * 512);
  size_t oS3   = alloc((size_t)M * 512);
  size_t oS4   = alloc((size_t)M * 512);
  size_t oSX   = alloc((size_t)M * 512);
  size_t oSXb  = allocs((size_t)M * 512);
  size_t oS0b  = allocs((size_t)M * 512);
  size_t oVt   = allocs((size_t)M * 512);
  size_t oWqe  = allocs((size_t)256 * KQP);
  size_t oWyk  = allocs((size_t)512 * 512);
  size_t oWyv  = allocs((size_t)512 * 512);
  size_t oWyo  = allocs((size_t)512 * 512);
  size_t oWyf1 = allocs((size_t)2048 * 512);
  size_t oWyf2 = allocs((size_t)512 * 2048);
  size_t oWxk  = allocs((size_t)256 * 256);
  size_t oWxv  = allocs((size_t)256 * 256);
  size_t oWxo  = allocs((size_t)256 * 256);
  size_t oWhk  = allocs((size_t)256 * 256);
  size_t oWhv  = allocs((size_t)512 * 512);
  size_t oWho  = allocs((size_t)256 * 512);
  size_t oWhf1 = allocs((size_t)2048 * 256);
  size_t oWhf2 = allocs((size_t)256 * 2048);
  size_t oWo1  = allocs((size_t)512 * 512);
  size_t oWo2  = allocs((size_t)256 * 512);
  (void)ws_size; (void)in_sizes; (void)n_in; (void)out_size;

  float* E    = ws + oE;
  unsigned short* SIGb = (unsigned short*)(ws + oSIGb);
  float* SSUM = ws + oSSUM;
  float* QE   = ws + oQE;   unsigned short* QEb = (unsigned short*)(ws + oQEb);
  float* QA   = ws + oQA;   unsigned short* QAb = (unsigned short*)(ws + oQAb);
  unsigned short* YOb = (unsigned short*)(ws + oYOb);
  float* XO   = ws + oXO;   unsigned short* XOb = (unsigned short*)(ws + oXOb);
  float* HO   = ws + oHO;
  float* S0   = ws + oS0;
  unsigned short* S2b = (unsigned short*)(ws + oS2b);
  float* S3   = ws + oS3;
  float* S4   = ws + oS4;
  float* SX   = ws + oSX;   unsigned short* SXb = (unsigned short*)(ws + oSXb);
  unsigned short* S0b = (unsigned short*)(ws + oS0b);
  unsigned short* Vt  = (unsigned short*)(ws + oVt);
  unsigned short* FFb = (unsigned short*)S0;

  unsigned short* Wqe  = (unsigned short*)(ws + oWqe);
  unsigned short* Wyk  = (unsigned short*)(ws + oWyk);
  unsigned short* Wyv  = (unsigned short*)(ws + oWyv);
  unsigned short* Wyo  = (unsigned short*)(ws + oWyo);
  unsigned short* Wyf1 = (unsigned short*)(ws + oWyf1);
  unsigned short* Wyf2 = (unsigned short*)(ws + oWyf2);
  unsigned short* Wxk  = (unsigned short*)(ws + oWxk);
  unsigned short* Wxv  = (unsigned short*)(ws + oWxv);
  unsigned short* Wxo  = (unsigned short*)(ws + oWxo);
  unsigned short* Whk  = (unsigned short*)(ws + oWhk);
  unsigned short* Whv  = (unsigned short*)(ws + oWhv);
  unsigned short* Who  = (unsigned short*)(ws + oWho);
  unsigned short* Whf1 = (unsigned short*)(ws + oWhf1);
  unsigned short* Whf2 = (unsigned short*)(ws + oWhf2);
  unsigned short* Wo1  = (unsigned short*)(ws + oWo1);
  unsigned short* Wo2  = (unsigned short*)(ws + oWo2);

  dim3 blk(256);
  int nElem512 = (8192 * 512 + 255) / 256;

  // ---- fused weight transposes ----
  {
    struct HD { const float* src; unsigned short* dst; int K, N, Kp; };
    const HD hd[16] = {
      {qemb_W, Wqe, KQ, 256, KQP},
      {y_kW, Wyk, 512, 512, 512}, {y_vW, Wyv, 512, 512, 512}, {y_oW, Wyo, 512, 512, 512},
      {y_f1W, Wyf1, 512, 2048, 512}, {y_f2W, Wyf2, 2048, 512, 2048},
      {x_kW, Wxk, 256, 256, 256}, {x_vW, Wxv, 256, 256, 256}, {x_oW, Wxo, 256, 256, 256},
      {h_kW, Whk, 256, 256, 256}, {h_vW, Whv, 512, 512, 512}, {h_oW, Who, 512, 256, 512},
      {h_f1W, Whf1, 256, 2048, 256}, {h_f2W, Whf2, 2048, 256, 2048},
      {o1W, Wo1, 512, 512, 512}, {o2W, Wo2, 512, 256, 512},
    };
    TPack P;
    int tot = 0;
    for (int k = 0; k < 16; ++k) {
      int tx = (hd[k].N + 31) / 32, ty = (hd[k].Kp + 31) / 32;
      P.d[k] = { hd[k].src, hd[k].dst, hd[k].K, hd[k].N, hd[k].Kp, tx, tot };
      tot += tx * ty;
    }
    tconv_all_kernel<<<dim3(tot), blk, 0, stream>>>(P);
  }

  auto gg = [](int BMv, int TNv, int Mm, int Nn) {
    return dim3((unsigned)(Nn / TNv), (unsigned)((Mm + BMv - 1) / BMv));
  };

  // 1. embedding table
  sig_kernel<<<R, blk, 0, stream>>>(pemb_W, SIGb, SSUM, KQ, KQP);
  mgemm_kernel<64, 64, 2, true, false, false><<<gg(64, 64, R, 256), blk, 0, stream>>>(SIGb, Wqe, qemb_b, E, nullptr, nullptr, R, 256, KQP, SSUM, nullptr, 0);
  gather_kernel<<<nElem512, blk, 0, stream>>>(p_data, pa_data, E, diff_W, QE, QEb, QA, QAb);
  creg_kernel<<<1, blk, 0, stream>>>(p_data, diff_W, out_f + 8192);

  dim3 ablk(512);
  dim3 lgrid(M / 4);
  dim3 agA(64, B * NHEADS);

  // 2. y layer (dm=512, mask_k=1, zero_pad=0, FFN). Fused KV proj.
  mgemm_kernel<128, 64, 0, false, true, true><<<gg(128, 64, M, 1024), blk, 0, stream>>>(QAb, Wyk, y_kb, nullptr, S0b, Vt, M, 1024, 512, nullptr, y_vb, 512);
  attnD_kernel<64, 64, 1, 0><<<agA, ablk, 0, stream>>>(S0b, Vt, y_gam, S2b, S, M);
  mgemm_kernel<128, 64, 0, true, false, false><<<gg(128, 64, M, 512), blk, 0, stream>>>(S2b, Wyo, y_ob, S3, nullptr, nullptr, M, 512, 512, nullptr, nullptr, 0);
  ln4_kernel<512, true, true><<<lgrid, blk, 0, stream>>>(QA, S3, y_ln1g, y_ln1b, SX, SXb);
  mgemm_kernel<128, 128, 1, false, true, false><<<gg(128, 128, M, 2048), blk, 0, stream>>>(SXb, Wyf1, y_f1b, nullptr, FFb, nullptr, M, 2048, 512, nullptr, nullptr, 0);
  mgemm_kernel<128, 64, 0, true, false, false><<<gg(128, 64, M, 512), blk, 0, stream>>>(FFb, Wyf2, y_f2b, S4, nullptr, nullptr, M, 512, 2048, nullptr, nullptr, 0);
  ln4_kernel<512, false, true><<<lgrid, blk, 0, stream>>>(SX, S4, y_ln2g, y_ln2b, nullptr, YOb);

  // 3. x layer (dm=256, mask_k=1, zero_pad=0, no FFN). Fused KV proj.
  mgemm_kernel<128, 64, 0, false, true, true><<<gg(128, 64, M, 512), blk, 0, stream>>>(QEb, Wxk, x_kb, nullptr, S0b, Vt, M, 512, 256, nullptr, x_vb, 256);
  attnD_kernel<32, 32, 1, 0><<<agA, ablk, 0, stream>>>(S0b, Vt, x_gam, S2b, S, M);
  mgemm_kernel<64, 64, 0, true, false, false><<<gg(64, 64, M, 256), blk, 0, stream>>>(S2b, Wxo, x_ob, S3, nullptr, nullptr, M, 256, 256, nullptr, nullptr, 0);
  ln4_kernel<256, true, true><<<lgrid, blk, 0, stream>>>(QE, S3, x_ln1g, x_ln1b, XO, XOb);

  // 4. h layer (q,k from XO; v from YO; mask_k=0, zero_pad=1, FFN)
  mgemm_kernel<64, 64, 0, false, true, false><<<gg(64, 64, M, 256), blk, 0, stream>>>(XOb, Whk, h_kb, nullptr, S0b, nullptr, M, 256, 256, nullptr, nullptr, 0);
  mgemm_kernel<128, 64, 0, false, false, true><<<gg(128, 64, M, 512), blk, 0, stream>>>(YOb, Whv, h_vb, nullptr, nullptr, Vt, M, 512, 512, nullptr, nullptr, 0);
  attnD_kernel<32, 64, 0, 1><<<agA, ablk, 0, stream>>>(S0b, Vt, h_gam, S2b, S, M);
  mgemm_kernel<64, 64, 0, true, false, false><<<gg(64, 64, M, 256), blk, 0, stream>>>(S2b, Who, h_ob, S3, nullptr, nullptr, M, 256, 512, nullptr, nullptr, 0);
  ln4_kernel<256, true, true><<<lgrid, blk, 0, stream>>>(XO, S3, h_ln1g, h_ln1b, SX, SXb);
  mgemm_kernel<128, 128, 1, false, true, false><<<gg(128, 128, M, 2048), blk, 0, stream>>>(SXb, Whf1, h_f1b, nullptr, FFb, nullptr, M, 2048, 256, nullptr, nullptr, 0);
  mgemm_kernel<64, 64, 0, true, false, false><<<gg(64, 64, M, 256), blk, 0, stream>>>(FFb, Whf2, h_f2b, S4, nullptr, nullptr, M, 256, 2048, nullptr, nullptr, 0);
  ln4_kernel<256, true, false><<<lgrid, blk, 0, stream>>>(SX, S4, h_ln2g, h_ln2b, HO, nullptr);

  // 5. head: LN(concat) -> o1 -> LN -> o2 -> LN+dot
  lnc_kernel<<<lgrid, blk, 0, stream>>>(HO, QE, oln1g, oln1b, SXb);
  mgemm_kernel<128, 64, 1, true, false, false><<<gg(128, 64, M, 512), blk, 0, stream>>>(SXb, Wo1, o1b, S3, nullptr, nullptr, M, 512, 512, nullptr, nullptr, 0);
  ln4_kernel<512, false, true><<<lgrid, blk, 0, stream>>>(S3, nullptr, oln2g, oln2b, nullptr, SXb);
  mgemm_kernel<64, 64, 1, true, false, false><<<gg(64, 64, M, 256), blk, 0, stream>>>(SXb, Wo2, o2b, S4, nullptr, nullptr, M, 256, 512, nullptr, nullptr, 0);
  lndot_kernel<<<lgrid, blk, 0, stream>>>(S4, oln3g, oln3b, o3W, o3b, out_f);
}

// Round 17
// 714.637 us; speedup vs baseline: 1.0103x; 1.0103x over previous
//
#include <hip/hip_runtime.h>
#include <hip/hip_bf16.h>
#include <math.h>

#define NHEADS 8
#define L2E 1.44269504f

typedef __attribute__((ext_vector_type(8))) __bf16 bfrag;
typedef __attribute__((ext_vector_type(4))) float f32x4;
typedef __attribute__((ext_vector_type(8))) unsigned short u16x8;

static __device__ __forceinline__ unsigned short f2bf(float f) {
  unsigned u = __float_as_uint(f);
  unsigned r = (u + 0x7fffu + ((u >> 16) & 1u)) >> 16;
  return (unsigned short)r;
}

static __device__ __forceinline__ void gload_lds16(const void* g, void* l) {
  __builtin_amdgcn_global_load_lds(
      (const __attribute__((address_space(1))) unsigned int*)g,
      (__attribute__((address_space(3))) unsigned int*)l, 16, 0, 0);
}

static __device__ __forceinline__ float block_reduce_sum(float v, float* red) {
  int t = threadIdx.x;
  red[t] = v; __syncthreads();
  for (int s = 128; s > 0; s >>= 1) {
    if (t < s) red[t] += red[t + s];
    __syncthreads();
  }
  float r = red[0];
  __syncthreads();
  return r;
}

// ---------------- sigmoid table (bf16, padded to Kp) + row sums ----------------
__global__ __launch_bounds__(256) void sig_kernel(
    const float* __restrict__ Wp, unsigned short* __restrict__ Sgb,
    float* __restrict__ Ssum, int Kd, int Kp)
{
  __shared__ float red[256];
  int row = blockIdx.x;
  float s = 0.f;
  for (int k = threadIdx.x; k < Kp; k += 256) {
    float v = 0.f;
    if (k < Kd) {
      v = 1.f / (1.f + __expf(-Wp[(size_t)row * Kd + k]));
      s += v;
    }
    Sgb[(size_t)row * Kp + k] = f2bf(v);
  }
  float tot = block_reduce_sum(s, red);
  if (threadIdx.x == 0) Ssum[row] = tot;
}

// ---------------- fused transpose+convert for all weights ----------------
struct TDesc { const float* src; unsigned short* dst; int K, N, Kp, tilesX, blk0; };
struct TPack { TDesc d[16]; };

__global__ __launch_bounds__(256) void tconv_all_kernel(TPack P) {
  __shared__ float t[32][33];
  int bid = blockIdx.x;
  int di = 0;
  #pragma unroll
  for (int k = 1; k < 16; ++k) if (bid >= P.d[k].blk0) di = k;
  const float* src = P.d[di].src;
  unsigned short* dst = P.d[di].dst;
  int K = P.d[di].K, N = P.d[di].N, Kp = P.d[di].Kp, tilesX = P.d[di].tilesX;
  int local = bid - P.d[di].blk0;
  int bn = (local % tilesX) * 32;
  int bk = (local / tilesX) * 32;
  int tid = threadIdx.x;
  int tx = tid & 31, ty = tid >> 5;
  #pragma unroll
  for (int u = 0; u < 4; ++u) {
    int k = bk + ty + u * 8, n = bn + tx;
    t[ty + u * 8][tx] = (k < K && n < N) ? src[(size_t)k * N + n] : 0.f;
  }
  __syncthreads();
  #pragma unroll
  for (int u = 0; u < 4; ++u) {
    int n = bn + ty + u * 8, kk = bk + tx;
    if (n < N && kk < Kp)
      dst[(size_t)n * Kp + kk] = f2bf(t[tx][ty + u * 8]);
  }
}

// ---------------- MFMA bf16 GEMM: C = epi(A @ Bt^T + bias) ----------------
// Tiles: (BM,TN) in {(128,128),(128,64),(64,64)}. 4 waves = 2x2.
template<int BM, int TN, int EPI, bool WF32, bool WBF, bool WTR>
__global__ __launch_bounds__(256) void mgemm_kernel(
    const unsigned short* __restrict__ A, const unsigned short* __restrict__ Bt,
    const float* __restrict__ bias, float* __restrict__ C,
    unsigned short* __restrict__ Cb, unsigned short* __restrict__ Ct,
    int M, int N, int K, const float* __restrict__ divv,
    const float* __restrict__ bias2, int Nk)
{
  constexpr int NI = BM / 32, NJ = TN / 32;
  constexpr int WR = BM / 2, WC = TN / 2;
  constexpr bool SPLIT = WBF && WTR;
  __shared__ __align__(16) unsigned short Als[BM * 32];
  __shared__ __align__(16) unsigned short Bls[TN * 32];
  const int tid = threadIdx.x;
  const int lane = tid & 63, w = tid >> 6;
  const int wm = w >> 1, wn = w & 1;
  const int brow = blockIdx.y * BM, bcol = blockIdx.x * TN;

  f32x4 acc[NI][NJ] = {};

  for (int k0 = 0; k0 < K; k0 += 32) {
    if constexpr (TN == 128) {
      #pragma unroll
      for (int q = 0; q < 2; ++q) {
        int s = w * 128 + q * 64 + lane;
        int r = s >> 2, g = s & 3;
        int gs = g ^ (r & 3);
        int gc = bcol + r; if (gc > N - 1) gc = N - 1;
        gload_lds16(Bt + (size_t)gc * K + k0 + gs * 8,
                    (char*)Bls + (w * 2048 + q * 1024));
      }
    } else {
      int s = tid;
      int r = s >> 2, g = s & 3;
      int gs = g ^ (r & 3);
      int gc = bcol + r; if (gc > N - 1) gc = N - 1;
      gload_lds16(Bt + (size_t)gc * K + k0 + gs * 8,
                  (char*)Bls + w * 1024);
    }
    if constexpr (BM == 128) {
      #pragma unroll
      for (int q = 0; q < 2; ++q) {
        int s = w * 128 + q * 64 + lane;
        int r = s >> 2, g = s & 3;
        int gs = g ^ (r & 3);
        int gr = brow + r; if (gr > M - 1) gr = M - 1;
        gload_lds16(A + (size_t)gr * K + k0 + gs * 8,
                    (char*)Als + (w * 2048 + q * 1024));
      }
    } else {
      int s = tid;
      int r = s >> 2, g = s & 3;
      int gs = g ^ (r & 3);
      int gr = brow + r; if (gr > M - 1) gr = M - 1;
      gload_lds16(A + (size_t)gr * K + k0 + gs * 8,
                  (char*)Als + w * 1024);
    }
    __syncthreads();

    bfrag av[NI], bv[NJ];
    #pragma unroll
    for (int f = 0; f < NI; ++f) {
      int rA = wm * WR + f * 16 + (lane & 15);
      av[f] = *(const bfrag*)((const char*)Als + rA * 64 + ((((lane >> 4) ^ (rA & 3))) << 4));
    }
    #pragma unroll
    for (int f = 0; f < NJ; ++f) {
      int rB = wn * WC + f * 16 + (lane & 15);
      bv[f] = *(const bfrag*)((const char*)Bls + rB * 64 + ((((lane >> 4) ^ (rB & 3))) << 4));
    }
    #pragma unroll
    for (int i = 0; i < NI; ++i)
      #pragma unroll
      for (int j = 0; j < NJ; ++j)
        acc[i][j] = __builtin_amdgcn_mfma_f32_16x16x32_bf16(av[i], bv[j], acc[i][j], 0, 0, 0);
    __syncthreads();
  }

  #pragma unroll
  for (int i = 0; i < NI; ++i) {
    int gr0 = brow + wm * WR + i * 16 + (lane >> 4) * 4;
    #pragma unroll
    for (int j = 0; j < NJ; ++j) {
      int gc = bcol + wn * WC + j * 16 + (lane & 15);
      float bsv;
      if (SPLIT) bsv = (gc < Nk) ? bias[gc] : bias2[gc - Nk];
      else       bsv = bias ? bias[gc] : 0.f;
      float vv[4];
      #pragma unroll
      for (int q = 0; q < 4; ++q) {
        int gr = gr0 + q;
        float v = acc[i][j][q] + bsv;
        if (EPI >= 1) v = fmaxf(v, 0.f);
        if (EPI == 2) v = (gr < M) ? v / divv[gr] : v;
        vv[q] = v;
      }
      if (SPLIT) {
        if (gc < Nk) {
          #pragma unroll
          for (int q = 0; q < 4; ++q) {
            int gr = gr0 + q;
            if (gr < M) Cb[(size_t)gr * Nk + gc] = f2bf(vv[q]);
          }
        } else {
          ushort4 h4 = { f2bf(vv[0]), f2bf(vv[1]), f2bf(vv[2]), f2bf(vv[3]) };
          *(ushort4*)(Ct + (size_t)(gc - Nk) * M + gr0) = h4;
        }
      } else {
        #pragma unroll
        for (int q = 0; q < 4; ++q) {
          int gr = gr0 + q;
          if (gr >= M) continue;
          if (WF32) C[(size_t)gr * N + gc] = vv[q];
          if (WBF)  Cb[(size_t)gr * N + gc] = f2bf(vv[q]);
        }
        if (WTR) {
          ushort4 h4 = { f2bf(vv[0]), f2bf(vv[1]), f2bf(vv[2]), f2bf(vv[3]) };
          *(ushort4*)(Ct + (size_t)gc * M + gr0) = h4;
        }
      }
    }
  }
}

// ---------------- embedding gather ----------------
__global__ __launch_bounds__(256) void gather_kernel(
    const int* __restrict__ p_data, const int* __restrict__ pa_data,
    const float* __restrict__ E, const float* __restrict__ diff_W,
    float* __restrict__ qemb, unsigned short* __restrict__ qembb,
    float* __restrict__ qaemb, unsigned short* __restrict__ qaembb)
{
  int idx = blockIdx.x * 256 + threadIdx.x;
  if (idx >= 8192 * 512) return;
  int row = idx >> 9, c = idx & 511;
  int p = p_data[row];
  float pid = diff_W[p];
  if (c < 256) {
    float v = E[(size_t)p * 256 + c] + pid;
    qemb[(size_t)row * 256 + c] = v;
    qembb[(size_t)row * 256 + c] = f2bf(v);
  }
  int pa = pa_data[row];
  int ppos = (pa > 4096) ? pa - 4096 : 0;
  int pneg = (pa <= 4096) ? pa : 0;
  float v = (c < 256) ? E[(size_t)ppos * 256 + c] : E[(size_t)pneg * 256 + (c - 256)];
  v += pid;
  qaemb[(size_t)row * 512 + c] = v;
  qaembb[(size_t)row * 512 + c] = f2bf(v);
}

// ---------------- c_reg ----------------
__global__ __launch_bounds__(256) void creg_kernel(
    const int* __restrict__ p_data, const float* __restrict__ dW,
    float* __restrict__ out)
{
  __shared__ float red[256];
  float s = 0.f;
  for (int i = threadIdx.x; i < 8192; i += 256) {
    float v = dW[p_data[i]];
    s += v * v;
  }
  float tot = block_reduce_sum(s, red);
  if (threadIdx.x == 0) out[0] = tot * 1e-5f;
}

// ---------------- MFMA distance-decay attention v14: 3-pass streaming softmax ----------------
// Uses safe bound mS = max(m1,0) >= p' for the final exp (eff <= 1; softmax
// normalization divides it out -> mathematically identical).
template<int DK, int DV, int MASKK, int ZP>
__global__ __launch_bounds__(512, 4) void attnC_kernel(
    const unsigned short* __restrict__ QKb, const unsigned short* __restrict__ Vt,
    const float* __restrict__ gamp, unsigned short* __restrict__ O,
    int S, int MT)
{
  constexpr int RS = 1156;
  constexpr int NPAR = (DV == 64) ? 2 : 4;
  constexpr int NFIN = (DV == 64) ? 4 : 2;
  constexpr int NP   = (DV == 32) ? 6 : 4;
  const int DMK = NHEADS * DK, DMV = NHEADS * DV;
  const int id = blockIdx.x + blockIdx.y * 64;
  const int W = (id & 7) * 512 + (id >> 3);     // XCD-chunked bijection (4096 blocks)
  const int ib = 63 - (W & 63);                 // descending-NK order
  const int bh = W >> 6;
  const int i0 = ib * 16;
  const int b = bh >> 3, h = bh & 7;
  const int tid = threadIdx.x;
  const int lane = tid & 63, w = tid >> 6;
  const size_t rowbase = (size_t)b * S;

  __shared__ __align__(16) float sc[16 * RS];
  __shared__ float wrow[16];

  const int jmaxBlk = MASKK ? (i0 + 15) : (i0 + 14);
  const int NK = (jmaxBlk / 64 + 1) * 64;
  const int NKp = (NK + 255) & ~255;            // 256..1024
  const int CD = NKp >> 5;                      // 8,16,24,32 elems/lane

  const int qr = lane & 15;
  const int ko8 = (lane >> 4) * 8;
  const float rscale = rsqrtf((float)DK) * L2E;

  bfrag qf[DK / 32];
  #pragma unroll
  for (int ks = 0; ks < DK / 32; ++ks)
    qf[ks] = *(const bfrag*)(QKb + (rowbase + i0 + qr) * DMK + h * DK + ks * 32 + ko8);

  // ---- QK^T (rscale*L2E folded into scatter) ----
  for (int t0 = 0; t0 < NK; t0 += 128) {
    int tt = t0 + (w >> 2) * 64;
    if (tt < NK) {
      int jb = tt + (w & 3) * 16 + qr;
      bfrag kf[DK / 32];
      #pragma unroll
      for (int ks = 0; ks < DK / 32; ++ks)
        kf[ks] = *(const bfrag*)(QKb + (rowbase + jb) * DMK + h * DK + ks * 32 + ko8);
      f32x4 accs = {};
      __builtin_amdgcn_s_setprio(1);
      #pragma unroll
      for (int ks = 0; ks < DK / 32; ++ks)
        accs = __builtin_amdgcn_mfma_f32_16x16x32_bf16(qf[ks], kf[ks], accs, 0, 0, 0);
      __builtin_amdgcn_s_setprio(0);
      int ja = jb + 4 * (jb >> 5);
      int r0 = (lane >> 4) * 4;
      #pragma unroll
      for (int q = 0; q < 4; ++q)
        sc[(r0 + q) * RS + ja] = accs[q] * rscale;
    }
  }
  __syncthreads();

  // ---- streaming softmax (exp2 domain), 3 passes ----
  {
    const int g = tid >> 5, l = tid & 31;
    const int i = i0 + g;
    const int jmax = MASKK ? i : i - 1;
    const int jb0 = CD * l;
    const int CD4 = CD >> 2;
    float* rowF = sc + g * RS;

    // P1: max
    float m1 = -1e30f;
    for (int c = 0; c < CD4; ++c) {
      int j = jb0 + 4 * c;
      f32x4 v = *(const f32x4*)(rowF + j + 4 * (j >> 5));
      #pragma unroll
      for (int k = 0; k < 4; ++k)
        m1 = fmaxf(m1, (j + k <= jmax) ? v[k] : -1e30f);
    }
    #pragma unroll
    for (int o = 16; o > 0; o >>= 1) m1 = fmaxf(m1, __shfl_xor(m1, o, 32));

    // P2: lane-local sum of exp2
    float lloc = 0.f;
    for (int c = 0; c < CD4; ++c) {
      int j = jb0 + 4 * c;
      f32x4 v = *(const f32x4*)(rowF + j + 4 * (j >> 5));
      #pragma unroll
      for (int k = 0; k < 4; ++k)
        lloc += (j + k <= jmax) ? __builtin_amdgcn_exp2f(v[k] - m1) : 0.f;
    }
    float l1 = lloc;
    #pragma unroll
    for (int o = 16; o > 0; o >>= 1) l1 += __shfl_xor(l1, o, 32);

    float scn = lloc;
    #pragma unroll
    for (int o = 1; o < 32; o <<= 1) {
      float u = __shfl_up(scn, o, 32);
      if (l >= o) scn += u;
    }
    float cum = scn - lloc;

    float gv = gamp[h];
    float sp = fmaxf(gv, 0.f) + log1pf(__expf(-fabsf(gv)));
    float gmr = -sp * L2E * rsqrtf(l1);
    float mS = fmaxf(m1, 0.f);     // safe upper bound on p' = s*eff (eff <= 1)

    // P3: cum/effect + final exp2 + bf16 planes, all in one pass
    float l2 = 0.f;
    for (int c = 0; c < CD4; c += 2) {
      int jo = jb0 + 4 * c;
      char* base = (char*)(rowF + jo + 4 * (jo >> 5));
      f32x4 a = *(const f32x4*)base;
      f32x4 bq = *(const f32x4*)(base + 16);
      u16x8 hi8, lo8;
      #pragma unroll
      for (int e = 0; e < 8; ++e) {
        int jj = jo + e;
        float sv = (e < 4) ? a[e] : bq[e - 4];
        bool ok = jj <= jmax;
        float e1 = ok ? __builtin_amdgcn_exp2f(sv - m1) : 0.f;
        cum += e1;
        float rem = fmaxf(l1 - cum, 0.f);
        float dsq = sqrtf(rem * fabsf((float)(i - jj)));
        float eff = fmaxf(__builtin_amdgcn_exp2f(gmr * dsq), 1e-5f);
        float ev = ok ? __builtin_amdgcn_exp2f(sv * eff - mS) : 0.f;
        l2 += ev;
        __bf16 hb = (__bf16)ev;
        hi8[e] = __builtin_bit_cast(unsigned short, hb);
        lo8[e] = __builtin_bit_cast(unsigned short, (__bf16)(ev - (float)hb));
      }
      *(u16x8*)base = hi8;
      *(u16x8*)(base + 16) = lo8;
    }
    #pragma unroll
    for (int o = 16; o > 0; o >>= 1) l2 += __shfl_xor(l2, o, 32);
    bool validrow = (jmax >= 0) && !(ZP && i == 0);
    float wgt = validrow ? (1.f / l2) : 0.f;
    if (l == 0) wrow[g] = wgt;
  }
  __syncthreads();

  // ---- PV: wave owns (d-block, tile-parity); planes at 4*(jo+4*(jo>>5)) ----
  const int dblk = (DV == 64) ? (w & 3) : (w & 1);
  const int par  = (DV == 64) ? (w >> 2) : (w >> 1);
  const int dcol = h * DV + dblk * 16 + (lane & 15);
  const unsigned short* vrow = Vt + (size_t)dcol * MT + rowbase;
  f32x4 acco = {};
  const float* rowF = sc + qr * RS;
  __builtin_amdgcn_s_setprio(1);
  for (int t0 = par * 64; t0 < NK; t0 += NPAR * 64) {
    #pragma unroll
    for (int ks = 0; ks < 2; ++ks) {
      int jo = t0 + ks * 32 + ko8;
      const char* base = (const char*)(rowF + jo + 4 * (jo >> 5));
      bfrag ph = *(const bfrag*)base;
      bfrag pl = *(const bfrag*)(base + 16);
      bfrag vf = *(const bfrag*)(vrow + jo);
      acco = __builtin_amdgcn_mfma_f32_16x16x32_bf16(pl, vf, acco, 0, 0, 0);
      acco = __builtin_amdgcn_mfma_f32_16x16x32_bf16(ph, vf, acco, 0, 0, 0);
    }
  }
  __builtin_amdgcn_s_setprio(0);
  __syncthreads();                 // all plane reads complete; sc reusable

  float* redA = sc;                // alias partial-reduce buffer into sc
  if (w >= NFIN) {
    int slot = w - NFIN;
    #pragma unroll
    for (int q = 0; q < 4; ++q)
      redA[slot * 272 + ((lane >> 4) * 4 + q) * 17 + (lane & 15)] = acco[q];
  }
  __syncthreads();
  if (w < NFIN) {
    for (int pp = w; pp < NP; pp += NFIN) {
      #pragma unroll
      for (int q = 0; q < 4; ++q)
        acco[q] += redA[pp * 272 + ((lane >> 4) * 4 + q) * 17 + (lane & 15)];
    }
    int r0 = (lane >> 4) * 4;
    #pragma unroll
    for (int q = 0; q < 4; ++q) {
      float wv = wrow[r0 + q];
      O[(rowbase + i0 + r0 + q) * DMV + dcol] = f2bf(acco[q] * wv);
    }
  }
}

// ---------------- LayerNorm v4: one row per wave, float4 loads ----------------
template<int D, bool WF, bool WB>
__global__ __launch_bounds__(256) void ln4_kernel(
    const float* __restrict__ X, const float* __restrict__ R,
    const float* __restrict__ g, const float* __restrict__ be,
    float* __restrict__ Y, unsigned short* __restrict__ Yb)
{
  constexpr int NC = D / 256;
  int row = blockIdx.x * 4 + (threadIdx.x >> 6);
  int lane = threadIdx.x & 63;
  const float* x = X + (size_t)row * D;
  f32x4 xv[NC];
  float s = 0.f;
  #pragma unroll
  for (int c = 0; c < NC; ++c) {
    xv[c] = *(const f32x4*)(x + c * 256 + lane * 4);
    if (R) {
      f32x4 rv = *(const f32x4*)(R + (size_t)row * D + c * 256 + lane * 4);
      #pragma unroll
      for (int k = 0; k < 4; ++k) xv[c][k] += rv[k];
    }
    #pragma unroll
    for (int k = 0; k < 4; ++k) s += xv[c][k];
  }
  #pragma unroll
  for (int o = 32; o > 0; o >>= 1) s += __shfl_xor(s, o, 64);
  float mean = s / (float)D;
  float vs = 0.f;
  #pragma unroll
  for (int c = 0; c < NC; ++c)
    #pragma unroll
    for (int k = 0; k < 4; ++k) { float d = xv[c][k] - mean; vs += d * d; }
  #pragma unroll
  for (int o = 32; o > 0; o >>= 1) vs += __shfl_xor(vs, o, 64);
  float rstd = rsqrtf(vs / (float)D + 1e-5f);
  #pragma unroll
  for (int c = 0; c < NC; ++c) {
    f32x4 gv = *(const f32x4*)(g + c * 256 + lane * 4);
    f32x4 bv = *(const f32x4*)(be + c * 256 + lane * 4);
    f32x4 ov;
    #pragma unroll
    for (int k = 0; k < 4; ++k) ov[k] = gv[k] * (xv[c][k] - mean) * rstd + bv[k];
    if (WF) *(f32x4*)(Y + (size_t)row * D + c * 256 + lane * 4) = ov;
    if (WB) {
      ushort4 h4 = { f2bf(ov[0]), f2bf(ov[1]), f2bf(ov[2]), f2bf(ov[3]) };
      *(ushort4*)(Yb + (size_t)row * D + c * 256 + lane * 4) = h4;
    }
  }
}

// ---------------- fused concat + LN (D=512) ----------------
__global__ __launch_bounds__(256) void lnc_kernel(
    const float* __restrict__ Xh, const float* __restrict__ Qe,
    const float* __restrict__ g, const float* __restrict__ be,
    unsigned short* __restrict__ Yb)
{
  int row = blockIdx.x * 4 + (threadIdx.x >> 6);
  int lane = threadIdx.x & 63;
  f32x4 xv[2];
  xv[0] = *(const f32x4*)(Xh + (size_t)row * 256 + lane * 4);
  xv[1] = *(const f32x4*)(Qe + (size_t)row * 256 + lane * 4);
  float s = 0.f;
  #pragma unroll
  for (int c = 0; c < 2; ++c)
    #pragma unroll
    for (int k = 0; k < 4; ++k) s += xv[c][k];
  #pragma unroll
  for (int o = 32; o > 0; o >>= 1) s += __shfl_xor(s, o, 64);
  float mean = s / 512.f;
  float vs = 0.f;
  #pragma unroll
  for (int c = 0; c < 2; ++c)
    #pragma unroll
    for (int k = 0; k < 4; ++k) { float d = xv[c][k] - mean; vs += d * d; }
  #pragma unroll
  for (int o = 32; o > 0; o >>= 1) vs += __shfl_xor(vs, o, 64);
  float rstd = rsqrtf(vs / 512.f + 1e-5f);
  #pragma unroll
  for (int c = 0; c < 2; ++c) {
    f32x4 gv = *(const f32x4*)(g + c * 256 + lane * 4);
    f32x4 bv = *(const f32x4*)(be + c * 256 + lane * 4);
    ushort4 h4;
    #pragma unroll
    for (int k = 0; k < 4; ++k) {
      float ov = gv[k] * (xv[c][k] - mean) * rstd + bv[k];
      ((unsigned short*)&h4)[k] = f2bf(ov);
    }
    *(ushort4*)(Yb + (size_t)row * 512 + c * 256 + lane * 4) = h4;
  }
}

// ---------------- fused LN(D=256) + dot ----------------
__global__ __launch_bounds__(256) void lndot_kernel(
    const float* __restrict__ X, const float* __restrict__ g,
    const float* __restrict__ be, const float* __restrict__ w3,
    const float* __restrict__ b3, float* __restrict__ out)
{
  int row = blockIdx.x * 4 + (threadIdx.x >> 6);
  int lane = threadIdx.x & 63;
  f32x4 v = *(const f32x4*)(X + (size_t)row * 256 + lane * 4);
  float s = v[0] + v[1] + v[2] + v[3];
  #pragma unroll
  for (int o = 32; o > 0; o >>= 1) s += __shfl_xor(s, o, 64);
  float mean = s / 256.f;
  float vs = 0.f;
  #pragma unroll
  for (int k = 0; k < 4; ++k) { float d = v[k] - mean; vs += d * d; }
  #pragma unroll
  for (int o = 32; o > 0; o >>= 1) vs += __shfl_xor(vs, o, 64);
  float rstd = rsqrtf(vs / 256.f + 1e-5f);
  f32x4 gv = *(const f32x4*)(g + lane * 4);
  f32x4 bv = *(const f32x4*)(be + lane * 4);
  f32x4 wv = *(const f32x4*)(w3 + lane * 4);
  float d = 0.f;
  #pragma unroll
  for (int k = 0; k < 4; ++k)
    d += (gv[k] * (v[k] - mean) * rstd + bv[k]) * wv[k];
  #pragma unroll
  for (int o = 32; o > 0; o >>= 1) d += __shfl_xor(d, o, 64);
  if (lane == 0) out[row] = d + b3[0];
}

// ---------------- launch ----------------
extern "C" void kernel_launch(void* const* d_in, const int* in_sizes, int n_in,
                              void* d_out, int out_size, void* d_ws, size_t ws_size,
                              hipStream_t stream) {
  const int* p_data  = (const int*)d_in[0];
  const int* pa_data = (const int*)d_in[1];
  const float* pemb_W = (const float*)d_in[3];
  const float* diff_W = (const float*)d_in[4];
  const float* qemb_W = (const float*)d_in[5];
  const float* qemb_b = (const float*)d_in[6];
  const float* y_kW = (const float*)d_in[7];   const float* y_kb = (const float*)d_in[8];
  const float* y_vW = (const float*)d_in[9];   const float* y_vb = (const float*)d_in[10];
  const float* y_oW = (const float*)d_in[11];  const float* y_ob = (const float*)d_in[12];
  const float* y_gam = (const float*)d_in[13];
  const float* y_ln1g = (const float*)d_in[14]; const float* y_ln1b = (const float*)d_in[15];
  const float* y_f1W = (const float*)d_in[16]; const float* y_f1b = (const float*)d_in[17];
  const float* y_f2W = (const float*)d_in[18]; const float* y_f2b = (const float*)d_in[19];
  const float* y_ln2g = (const float*)d_in[20]; const float* y_ln2b = (const float*)d_in[21];
  const float* x_kW = (const float*)d_in[22];  const float* x_kb = (const float*)d_in[23];
  const float* x_vW = (const float*)d_in[24];  const float* x_vb = (const float*)d_in[25];
  const float* x_oW = (const float*)d_in[26];  const float* x_ob = (const float*)d_in[27];
  const float* x_gam = (const float*)d_in[28];
  const float* x_ln1g = (const float*)d_in[29]; const float* x_ln1b = (const float*)d_in[30];
  const float* h_kW = (const float*)d_in[31];  const float* h_kb = (const float*)d_in[32];
  const float* h_vW = (const float*)d_in[33];  const float* h_vb = (const float*)d_in[34];
  const float* h_oW = (const float*)d_in[35];  const float* h_ob = (const float*)d_in[36];
  const float* h_gam = (const float*)d_in[37];
  const float* h_ln1g = (const float*)d_in[38]; const float* h_ln1b = (const float*)d_in[39];
  const float* h_f1W = (const float*)d_in[40]; const float* h_f1b = (const float*)d_in[41];
  const float* h_f2W = (const float*)d_in[42]; const float* h_f2b = (const float*)d_in[43];
  const float* h_ln2g = (const float*)d_in[44]; const float* h_ln2b = (const float*)d_in[45];
  const float* oln1g = (const float*)d_in[46]; const float* oln1b = (const float*)d_in[47];
  const float* o1W = (const float*)d_in[48];   const float* o1b = (const float*)d_in[49];
  const float* oln2g = (const float*)d_in[50]; const float* oln2b = (const float*)d_in[51];
  const float* o2W = (const float*)d_in[52];   const float* o2b = (const float*)d_in[53];
  const float* oln3g = (const float*)d_in[54]; const float* oln3b = (const float*)d_in[55];
  const float* o3W = (const float*)d_in[56];   const float* o3b = (const float*)d_in[57];

  float* out_f = (float*)d_out;

  const int B = 8, S = 1024, M = B * S;
  const int R = 4097, KQ = 1025, KQP = 1056;

  float* ws = (float*)d_ws;
  size_t off = 0;
  auto alloc = [&](size_t nfloats) { size_t o = off; off += (nfloats + 255) & ~(size_t)255; return o; };
  auto allocs = [&](size_t nshorts) { return alloc((nshorts + 1) / 2); };

  size_t oE    = alloc((size_t)R * 256);
  size_t oSIGb = allocs((size_t)R * KQP);
  size_t oSSUM = alloc(R);
  size_t oQE   = alloc((size_t)M * 256);
  size_t oQEb  = allocs((size_t)M * 256);
  size_t oQA   = alloc((size_t)M * 512);
  size_t oQAb  = allocs((size_t)M * 512);
  size_t oYOb  = allocs((size_t)M * 512);
  size_t oXO   = alloc((size_t)M * 256);
  size_t oXOb  = allocs((size_t)M * 256);
  size_t oHO   = alloc((size_t)M * 256);
  size_t oS0   = alloc((size_t)M * 512);   // FFb arena (S0+S1)
  size_t oS1   = alloc((size_t)M * 512);
  size_t oS2b  = allocs((size_t)M * 512);
  size_t oS3   = alloc((size_t)M * 512);
  size_t oS4   = alloc((size_t)M * 512);
  size_t oSX   = alloc((size_t)M * 512);
  size_t oSXb  = allocs((size_t)M * 512);
  size_t oS0b  = allocs((size_t)M * 512);
  size_t oVt   = allocs((size_t)M * 512);
  size_t oWqe  = allocs((size_t)256 * KQP);
  size_t oWyk  = allocs((size_t)512 * 512);
  size_t oWyv  = allocs((size_t)512 * 512);
  size_t oWyo  = allocs((size_t)512 * 512);
  size_t oWyf1 = allocs((size_t)2048 * 512);
  size_t oWyf2 = allocs((size_t)512 * 2048);
  size_t oWxk  = allocs((size_t)256 * 256);
  size_t oWxv  = allocs((size_t)256 * 256);
  size_t oWxo  = allocs((size_t)256 * 256);
  size_t oWhk  = allocs((size_t)256 * 256);
  size_t oWhv  = allocs((size_t)512 * 512);
  size_t oWho  = allocs((size_t)256 * 512);
  size_t oWhf1 = allocs((size_t)2048 * 256);
  size_t oWhf2 = allocs((size_t)256 * 2048);
  size_t oWo1  = allocs((size_t)512 * 512);
  size_t oWo2  = allocs((size_t)256 * 512);
  (void)ws_size; (void)in_sizes; (void)n_in; (void)out_size;

  float* E    = ws + oE;
  unsigned short* SIGb = (unsigned short*)(ws + oSIGb);
  float* SSUM = ws + oSSUM;
  float* QE   = ws + oQE;   unsigned short* QEb = (unsigned short*)(ws + oQEb);
  float* QA   = ws + oQA;   unsigned short* QAb = (unsigned short*)(ws + oQAb);
  unsigned short* YOb = (unsigned short*)(ws + oYOb);
  float* XO   = ws + oXO;   unsigned short* XOb = (unsigned short*)(ws + oXOb);
  float* HO   = ws + oHO;
  float* S0   = ws + oS0;
  unsigned short* S2b = (unsigned short*)(ws + oS2b);
  float* S3   = ws + oS3;
  float* S4   = ws + oS4;
  float* SX   = ws + oSX;   unsigned short* SXb = (unsigned short*)(ws + oSXb);
  unsigned short* S0b = (unsigned short*)(ws + oS0b);
  unsigned short* Vt  = (unsigned short*)(ws + oVt);
  unsigned short* FFb = (unsigned short*)S0;

  unsigned short* Wqe  = (unsigned short*)(ws + oWqe);
  unsigned short* Wyk  = (unsigned short*)(ws + oWyk);
  unsigned short* Wyv  = (unsigned short*)(ws + oWyv);
  unsigned short* Wyo  = (unsigned short*)(ws + oWyo);
  unsigned short* Wyf1 = (unsigned short*)(ws + oWyf1);
  unsigned short* Wyf2 = (unsigned short*)(ws + oWyf2);
  unsigned short* Wxk  = (unsigned short*)(ws + oWxk);
  unsigned short* Wxv  = (unsigned short*)(ws + oWxv);
  unsigned short* Wxo  = (unsigned short*)(ws + oWxo);
  unsigned short* Whk  = (unsigned short*)(ws + oWhk);
  unsigned short* Whv  = (unsigned short*)(ws + oWhv);
  unsigned short* Who  = (unsigned short*)(ws + oWho);
  unsigned short* Whf1 = (unsigned short*)(ws + oWhf1);
  unsigned short* Whf2 = (unsigned short*)(ws + oWhf2);
  unsigned short* Wo1  = (unsigned short*)(ws + oWo1);
  unsigned short* Wo2  = (unsigned short*)(ws + oWo2);

  dim3 blk(256);
  int nElem512 = (8192 * 512 + 255) / 256;

  // ---- fused weight transposes ----
  {
    struct HD { const float* src; unsigned short* dst; int K, N, Kp; };
    const HD hd[16] = {
      {qemb_W, Wqe, KQ, 256, KQP},
      {y_kW, Wyk, 512, 512, 512}, {y_vW, Wyv, 512, 512, 512}, {y_oW, Wyo, 512, 512, 512},
      {y_f1W, Wyf1, 512, 2048, 512}, {y_f2W, Wyf2, 2048, 512, 2048},
      {x_kW, Wxk, 256, 256, 256}, {x_vW, Wxv, 256, 256, 256}, {x_oW, Wxo, 256, 256, 256},
      {h_kW, Whk, 256, 256, 256}, {h_vW, Whv, 512, 512, 512}, {h_oW, Who, 512, 256, 512},
      {h_f1W, Whf1, 256, 2048, 256}, {h_f2W, Whf2, 2048, 256, 2048},
      {o1W, Wo1, 512, 512, 512}, {o2W, Wo2, 512, 256, 512},
    };
    TPack P;
    int tot = 0;
    for (int k = 0; k < 16; ++k) {
      int tx = (hd[k].N + 31) / 32, ty = (hd[k].Kp + 31) / 32;
      P.d[k] = { hd[k].src, hd[k].dst, hd[k].K, hd[k].N, hd[k].Kp, tx, tot };
      tot += tx * ty;
    }
    tconv_all_kernel<<<dim3(tot), blk, 0, stream>>>(P);
  }

  auto gg = [](int BMv, int TNv, int Mm, int Nn) {
    return dim3((unsigned)(Nn / TNv), (unsigned)((Mm + BMv - 1) / BMv));
  };

  // 1. embedding table
  sig_kernel<<<R, blk, 0, stream>>>(pemb_W, SIGb, SSUM, KQ, KQP);
  mgemm_kernel<64, 64, 2, true, false, false><<<gg(64, 64, R, 256), blk, 0, stream>>>(SIGb, Wqe, qemb_b, E, nullptr, nullptr, R, 256, KQP, SSUM, nullptr, 0);
  gather_kernel<<<nElem512, blk, 0, stream>>>(p_data, pa_data, E, diff_W, QE, QEb, QA, QAb);
  creg_kernel<<<1, blk, 0, stream>>>(p_data, diff_W, out_f + 8192);

  dim3 ablk(512);
  dim3 lgrid(M / 4);
  dim3 agA(64, B * NHEADS);

  // 2. y layer (dm=512, mask_k=1, zero_pad=0, FFN). Fused KV proj.
  mgemm_kernel<128, 64, 0, false, true, true><<<gg(128, 64, M, 1024), blk, 0, stream>>>(QAb, Wyk, y_kb, nullptr, S0b, Vt, M, 1024, 512, nullptr, y_vb, 512);
  attnC_kernel<64, 64, 1, 0><<<agA, ablk, 0, stream>>>(S0b, Vt, y_gam, S2b, S, M);
  mgemm_kernel<128, 64, 0, true, false, false><<<gg(128, 64, M, 512), blk, 0, stream>>>(S2b, Wyo, y_ob, S3, nullptr, nullptr, M, 512, 512, nullptr, nullptr, 0);
  ln4_kernel<512, true, true><<<lgrid, blk, 0, stream>>>(QA, S3, y_ln1g, y_ln1b, SX, SXb);
  mgemm_kernel<128, 128, 1, false, true, false><<<gg(128, 128, M, 2048), blk, 0, stream>>>(SXb, Wyf1, y_f1b, nullptr, FFb, nullptr, M, 2048, 512, nullptr, nullptr, 0);
  mgemm_kernel<128, 64, 0, true, false, false><<<gg(128, 64, M, 512), blk, 0, stream>>>(FFb, Wyf2, y_f2b, S4, nullptr, nullptr, M, 512, 2048, nullptr, nullptr, 0);
  ln4_kernel<512, false, true><<<lgrid, blk, 0, stream>>>(SX, S4, y_ln2g, y_ln2b, nullptr, YOb);

  // 3. x layer (dm=256, mask_k=1, zero_pad=0, no FFN). Fused KV proj.
  mgemm_kernel<128, 64, 0, false, true, true><<<gg(128, 64, M, 512), blk, 0, stream>>>(QEb, Wxk, x_kb, nullptr, S0b, Vt, M, 512, 256, nullptr, x_vb, 256);
  attnC_kernel<32, 32, 1, 0><<<agA, ablk, 0, stream>>>(S0b, Vt, x_gam, S2b, S, M);
  mgemm_kernel<64, 64, 0, true, false, false><<<gg(64, 64, M, 256), blk, 0, stream>>>(S2b, Wxo, x_ob, S3, nullptr, nullptr, M, 256, 256, nullptr, nullptr, 0);
  ln4_kernel<256, true, true><<<lgrid, blk, 0, stream>>>(QE, S3, x_ln1g, x_ln1b, XO, XOb);

  // 4. h layer (q,k from XO; v from YO; mask_k=0, zero_pad=1, FFN)
  mgemm_kernel<64, 64, 0, false, true, false><<<gg(64, 64, M, 256), blk, 0, stream>>>(XOb, Whk, h_kb, nullptr, S0b, nullptr, M, 256, 256, nullptr, nullptr, 0);
  mgemm_kernel<128, 64, 0, false, false, true><<<gg(128, 64, M, 512), blk, 0, stream>>>(YOb, Whv, h_vb, nullptr, nullptr, Vt, M, 512, 512, nullptr, nullptr, 0);
  attnC_kernel<32, 64, 0, 1><<<agA, ablk, 0, stream>>>(S0b, Vt, h_gam, S2b, S, M);
  mgemm_kernel<64, 64, 0, true, false, false><<<gg(64, 64, M, 256), blk, 0, stream>>>(S2b, Who, h_ob, S3, nullptr, nullptr, M, 256, 512, nullptr, nullptr, 0);
  ln4_kernel<256, true, true><<<lgrid, blk, 0, stream>>>(XO, S3, h_ln1g, h_ln1b, SX, SXb);
  mgemm_kernel<128, 128, 1, false, true, false><<<gg(128, 128, M, 2048), blk, 0, stream>>>(SXb, Whf1, h_f1b, nullptr, FFb, nullptr, M, 2048, 256, nullptr, nullptr, 0);
  mgemm_kernel<64, 64, 0, true, false, false><<<gg(64, 64, M, 256), blk, 0, stream>>>(FFb, Whf2, h_f2b, S4, nullptr, nullptr, M, 256, 2048, nullptr, nullptr, 0);
  ln4_kernel<256, true, false><<<lgrid, blk, 0, stream>>>(SX, S4, h_ln2g, h_ln2b, HO, nullptr);

  // 5. head: LN(concat) -> o1 -> LN -> o2 -> LN+dot
  lnc_kernel<<<lgrid, blk, 0, stream>>>(HO, QE, oln1g, oln1b, SXb);
  mgemm_kernel<128, 64, 1, true, false, false><<<gg(128, 64, M, 512), blk, 0, stream>>>(SXb, Wo1, o1b, S3, nullptr, nullptr, M, 512, 512, nullptr, nullptr, 0);
  ln4_kernel<512, false, true><<<lgrid, blk, 0, stream>>>(S3, nullptr, oln2g, oln2b, nullptr, SXb);
  mgemm_kernel<64, 64, 1, true, false, false><<<gg(64, 64, M, 256), blk, 0, stream>>>(SXb, Wo2, o2b, S4, nullptr, nullptr, M, 256, 512, nullptr, nullptr, 0);
  lndot_kernel<<<lgrid, blk, 0, stream>>>(S4, oln3g, oln3b, o3W, o3b, out_f);
}

// Round 18
// 706.963 us; speedup vs baseline: 1.0213x; 1.0109x over previous
//
#include <hip/hip_runtime.h>
#include <hip/hip_bf16.h>
#include <math.h>

#define NHEADS 8
#define L2E 1.44269504f

typedef __attribute__((ext_vector_type(8))) __bf16 bfrag;
typedef __attribute__((ext_vector_type(4))) float f32x4;
typedef __attribute__((ext_vector_type(8))) unsigned short u16x8;

static __device__ __forceinline__ unsigned short f2bf(float f) {
  unsigned u = __float_as_uint(f);
  unsigned r = (u + 0x7fffu + ((u >> 16) & 1u)) >> 16;
  return (unsigned short)r;
}

static __device__ __forceinline__ void gload_lds16(const void* g, void* l) {
  __builtin_amdgcn_global_load_lds(
      (const __attribute__((address_space(1))) unsigned int*)g,
      (__attribute__((address_space(3))) unsigned int*)l, 16, 0, 0);
}

static __device__ __forceinline__ float block_reduce_sum(float v, float* red) {
  int t = threadIdx.x;
  red[t] = v; __syncthreads();
  for (int s = 128; s > 0; s >>= 1) {
    if (t < s) red[t] += red[t + s];
    __syncthreads();
  }
  float r = red[0];
  __syncthreads();
  return r;
}

// ---------------- sigmoid table (bf16, padded to Kp) + row sums ----------------
__global__ __launch_bounds__(256) void sig_kernel(
    const float* __restrict__ Wp, unsigned short* __restrict__ Sgb,
    float* __restrict__ Ssum, int Kd, int Kp)
{
  __shared__ float red[256];
  int row = blockIdx.x;
  float s = 0.f;
  for (int k = threadIdx.x; k < Kp; k += 256) {
    float v = 0.f;
    if (k < Kd) {
      v = 1.f / (1.f + __expf(-Wp[(size_t)row * Kd + k]));
      s += v;
    }
    Sgb[(size_t)row * Kp + k] = f2bf(v);
  }
  float tot = block_reduce_sum(s, red);
  if (threadIdx.x == 0) Ssum[row] = tot;
}

// ---------------- fused transpose+convert for all weights ----------------
struct TDesc { const float* src; unsigned short* dst; int K, N, Kp, tilesX, blk0; };
struct TPack { TDesc d[16]; };

__global__ __launch_bounds__(256) void tconv_all_kernel(TPack P) {
  __shared__ float t[32][33];
  int bid = blockIdx.x;
  int di = 0;
  #pragma unroll
  for (int k = 1; k < 16; ++k) if (bid >= P.d[k].blk0) di = k;
  const float* src = P.d[di].src;
  unsigned short* dst = P.d[di].dst;
  int K = P.d[di].K, N = P.d[di].N, Kp = P.d[di].Kp, tilesX = P.d[di].tilesX;
  int local = bid - P.d[di].blk0;
  int bn = (local % tilesX) * 32;
  int bk = (local / tilesX) * 32;
  int tid = threadIdx.x;
  int tx = tid & 31, ty = tid >> 5;
  #pragma unroll
  for (int u = 0; u < 4; ++u) {
    int k = bk + ty + u * 8, n = bn + tx;
    t[ty + u * 8][tx] = (k < K && n < N) ? src[(size_t)k * N + n] : 0.f;
  }
  __syncthreads();
  #pragma unroll
  for (int u = 0; u < 4; ++u) {
    int n = bn + ty + u * 8, kk = bk + tx;
    if (n < N && kk < Kp)
      dst[(size_t)n * Kp + kk] = f2bf(t[tx][ty + u * 8]);
  }
}

// ---------------- MFMA bf16 GEMM: C = epi(A @ Bt^T + bias), BK=64 ----------------
// Tiles: (BM,TN) in {(128,128),(128,64),(64,64)}. 4 waves = 2x2.
// Rows are 64 bf16 = 128B = 8 granules; swizzle involution gs = g ^ (r&7).
template<int BM, int TN, int EPI, bool WF32, bool WBF, bool WTR>
__global__ __launch_bounds__(256) void mgemm_kernel(
    const unsigned short* __restrict__ A, const unsigned short* __restrict__ Bt,
    const float* __restrict__ bias, float* __restrict__ C,
    unsigned short* __restrict__ Cb, unsigned short* __restrict__ Ct,
    int M, int N, int K, const float* __restrict__ divv,
    const float* __restrict__ bias2, int Nk)
{
  constexpr int NI = BM / 32, NJ = TN / 32;
  constexpr int WR = BM / 2, WC = TN / 2;
  constexpr int APASS = BM / 32, BPASS = TN / 32;   // staging passes (4KB each)
  constexpr bool SPLIT = WBF && WTR;
  __shared__ __align__(16) unsigned short Als[BM * 64];
  __shared__ __align__(16) unsigned short Bls[TN * 64];
  const int tid = threadIdx.x;
  const int lane = tid & 63, w = tid >> 6;
  const int wm = w >> 1, wn = w & 1;
  const int brow = blockIdx.y * BM, bcol = blockIdx.x * TN;

  f32x4 acc[NI][NJ] = {};

  for (int k0 = 0; k0 < K; k0 += 64) {
    #pragma unroll
    for (int q = 0; q < BPASS; ++q) {
      int s = q * 256 + tid;
      int r = s >> 3, g = s & 7;
      int gs = g ^ (r & 7);
      int gc = bcol + r; if (gc > N - 1) gc = N - 1;
      gload_lds16(Bt + (size_t)gc * K + k0 + gs * 8,
                  (char*)Bls + (q * 4096 + w * 1024));
    }
    #pragma unroll
    for (int q = 0; q < APASS; ++q) {
      int s = q * 256 + tid;
      int r = s >> 3, g = s & 7;
      int gs = g ^ (r & 7);
      int gr = brow + r; if (gr > M - 1) gr = M - 1;
      gload_lds16(A + (size_t)gr * K + k0 + gs * 8,
                  (char*)Als + (q * 4096 + w * 1024));
    }
    __syncthreads();

    #pragma unroll
    for (int ks = 0; ks < 2; ++ks) {
      bfrag av[NI], bv[NJ];
      #pragma unroll
      for (int f = 0; f < NI; ++f) {
        int rA = wm * WR + f * 16 + (lane & 15);
        int gsl = (ks * 4 + (lane >> 4)) ^ (rA & 7);
        av[f] = *(const bfrag*)((const char*)Als + rA * 128 + gsl * 16);
      }
      #pragma unroll
      for (int f = 0; f < NJ; ++f) {
        int rB = wn * WC + f * 16 + (lane & 15);
        int gsl = (ks * 4 + (lane >> 4)) ^ (rB & 7);
        bv[f] = *(const bfrag*)((const char*)Bls + rB * 128 + gsl * 16);
      }
      #pragma unroll
      for (int i = 0; i < NI; ++i)
        #pragma unroll
        for (int j = 0; j < NJ; ++j)
          acc[i][j] = __builtin_amdgcn_mfma_f32_16x16x32_bf16(av[i], bv[j], acc[i][j], 0, 0, 0);
    }
    __syncthreads();
  }

  #pragma unroll
  for (int i = 0; i < NI; ++i) {
    int gr0 = brow + wm * WR + i * 16 + (lane >> 4) * 4;
    #pragma unroll
    for (int j = 0; j < NJ; ++j) {
      int gc = bcol + wn * WC + j * 16 + (lane & 15);
      float bsv;
      if (SPLIT) bsv = (gc < Nk) ? bias[gc] : bias2[gc - Nk];
      else       bsv = bias ? bias[gc] : 0.f;
      float vv[4];
      #pragma unroll
      for (int q = 0; q < 4; ++q) {
        int gr = gr0 + q;
        float v = acc[i][j][q] + bsv;
        if (EPI >= 1) v = fmaxf(v, 0.f);
        if (EPI == 2) v = (gr < M) ? v / divv[gr] : v;
        vv[q] = v;
      }
      if (SPLIT) {
        if (gc < Nk) {
          #pragma unroll
          for (int q = 0; q < 4; ++q) {
            int gr = gr0 + q;
            if (gr < M) Cb[(size_t)gr * Nk + gc] = f2bf(vv[q]);
          }
        } else {
          ushort4 h4 = { f2bf(vv[0]), f2bf(vv[1]), f2bf(vv[2]), f2bf(vv[3]) };
          *(ushort4*)(Ct + (size_t)(gc - Nk) * M + gr0) = h4;
        }
      } else {
        #pragma unroll
        for (int q = 0; q < 4; ++q) {
          int gr = gr0 + q;
          if (gr >= M) continue;
          if (WF32) C[(size_t)gr * N + gc] = vv[q];
          if (WBF)  Cb[(size_t)gr * N + gc] = f2bf(vv[q]);
        }
        if (WTR) {
          ushort4 h4 = { f2bf(vv[0]), f2bf(vv[1]), f2bf(vv[2]), f2bf(vv[3]) };
          *(ushort4*)(Ct + (size_t)gc * M + gr0) = h4;
        }
      }
    }
  }
}

// ---------------- embedding gather ----------------
__global__ __launch_bounds__(256) void gather_kernel(
    const int* __restrict__ p_data, const int* __restrict__ pa_data,
    const float* __restrict__ E, const float* __restrict__ diff_W,
    float* __restrict__ qemb, unsigned short* __restrict__ qembb,
    float* __restrict__ qaemb, unsigned short* __restrict__ qaembb)
{
  int idx = blockIdx.x * 256 + threadIdx.x;
  if (idx >= 8192 * 512) return;
  int row = idx >> 9, c = idx & 511;
  int p = p_data[row];
  float pid = diff_W[p];
  if (c < 256) {
    float v = E[(size_t)p * 256 + c] + pid;
    qemb[(size_t)row * 256 + c] = v;
    qembb[(size_t)row * 256 + c] = f2bf(v);
  }
  int pa = pa_data[row];
  int ppos = (pa > 4096) ? pa - 4096 : 0;
  int pneg = (pa <= 4096) ? pa : 0;
  float v = (c < 256) ? E[(size_t)ppos * 256 + c] : E[(size_t)pneg * 256 + (c - 256)];
  v += pid;
  qaemb[(size_t)row * 512 + c] = v;
  qaembb[(size_t)row * 512 + c] = f2bf(v);
}

// ---------------- c_reg ----------------
__global__ __launch_bounds__(256) void creg_kernel(
    const int* __restrict__ p_data, const float* __restrict__ dW,
    float* __restrict__ out)
{
  __shared__ float red[256];
  float s = 0.f;
  for (int i = threadIdx.x; i < 8192; i += 256) {
    float v = dW[p_data[i]];
    s += v * v;
  }
  float tot = block_reduce_sum(s, red);
  if (threadIdx.x == 0) out[0] = tot * 1e-5f;
}

// ---------------- MFMA distance-decay attention v14: 3-pass streaming softmax ----------------
template<int DK, int DV, int MASKK, int ZP>
__global__ __launch_bounds__(512, 4) void attnC_kernel(
    const unsigned short* __restrict__ QKb, const unsigned short* __restrict__ Vt,
    const float* __restrict__ gamp, unsigned short* __restrict__ O,
    int S, int MT)
{
  constexpr int RS = 1156;
  constexpr int NPAR = (DV == 64) ? 2 : 4;
  constexpr int NFIN = (DV == 64) ? 4 : 2;
  constexpr int NP   = (DV == 32) ? 6 : 4;
  const int DMK = NHEADS * DK, DMV = NHEADS * DV;
  const int id = blockIdx.x + blockIdx.y * 64;
  const int W = (id & 7) * 512 + (id >> 3);     // XCD-chunked bijection (4096 blocks)
  const int ib = 63 - (W & 63);                 // descending-NK order
  const int bh = W >> 6;
  const int i0 = ib * 16;
  const int b = bh >> 3, h = bh & 7;
  const int tid = threadIdx.x;
  const int lane = tid & 63, w = tid >> 6;
  const size_t rowbase = (size_t)b * S;

  __shared__ __align__(16) float sc[16 * RS];
  __shared__ float wrow[16];

  const int jmaxBlk = MASKK ? (i0 + 15) : (i0 + 14);
  const int NK = (jmaxBlk / 64 + 1) * 64;
  const int NKp = (NK + 255) & ~255;            // 256..1024
  const int CD = NKp >> 5;                      // 8,16,24,32 elems/lane

  const int qr = lane & 15;
  const int ko8 = (lane >> 4) * 8;
  const float rscale = rsqrtf((float)DK) * L2E;

  bfrag qf[DK / 32];
  #pragma unroll
  for (int ks = 0; ks < DK / 32; ++ks)
    qf[ks] = *(const bfrag*)(QKb + (rowbase + i0 + qr) * DMK + h * DK + ks * 32 + ko8);

  // ---- QK^T (rscale*L2E folded into scatter) ----
  for (int t0 = 0; t0 < NK; t0 += 128) {
    int tt = t0 + (w >> 2) * 64;
    if (tt < NK) {
      int jb = tt + (w & 3) * 16 + qr;
      bfrag kf[DK / 32];
      #pragma unroll
      for (int ks = 0; ks < DK / 32; ++ks)
        kf[ks] = *(const bfrag*)(QKb + (rowbase + jb) * DMK + h * DK + ks * 32 + ko8);
      f32x4 accs = {};
      __builtin_amdgcn_s_setprio(1);
      #pragma unroll
      for (int ks = 0; ks < DK / 32; ++ks)
        accs = __builtin_amdgcn_mfma_f32_16x16x32_bf16(qf[ks], kf[ks], accs, 0, 0, 0);
      __builtin_amdgcn_s_setprio(0);
      int ja = jb + 4 * (jb >> 5);
      int r0 = (lane >> 4) * 4;
      #pragma unroll
      for (int q = 0; q < 4; ++q)
        sc[(r0 + q) * RS + ja] = accs[q] * rscale;
    }
  }
  __syncthreads();

  // ---- streaming softmax (exp2 domain), 3 passes ----
  {
    const int g = tid >> 5, l = tid & 31;
    const int i = i0 + g;
    const int jmax = MASKK ? i : i - 1;
    const int jb0 = CD * l;
    const int CD4 = CD >> 2;
    float* rowF = sc + g * RS;

    // P1: max
    float m1 = -1e30f;
    for (int c = 0; c < CD4; ++c) {
      int j = jb0 + 4 * c;
      f32x4 v = *(const f32x4*)(rowF + j + 4 * (j >> 5));
      #pragma unroll
      for (int k = 0; k < 4; ++k)
        m1 = fmaxf(m1, (j + k <= jmax) ? v[k] : -1e30f);
    }
    #pragma unroll
    for (int o = 16; o > 0; o >>= 1) m1 = fmaxf(m1, __shfl_xor(m1, o, 32));

    // P2: lane-local sum of exp2
    float lloc = 0.f;
    for (int c = 0; c < CD4; ++c) {
      int j = jb0 + 4 * c;
      f32x4 v = *(const f32x4*)(rowF + j + 4 * (j >> 5));
      #pragma unroll
      for (int k = 0; k < 4; ++k)
        lloc += (j + k <= jmax) ? __builtin_amdgcn_exp2f(v[k] - m1) : 0.f;
    }
    float l1 = lloc;
    #pragma unroll
    for (int o = 16; o > 0; o >>= 1) l1 += __shfl_xor(l1, o, 32);

    float scn = lloc;
    #pragma unroll
    for (int o = 1; o < 32; o <<= 1) {
      float u = __shfl_up(scn, o, 32);
      if (l >= o) scn += u;
    }
    float cum = scn - lloc;

    float gv = gamp[h];
    float sp = fmaxf(gv, 0.f) + log1pf(__expf(-fabsf(gv)));
    float gmr = -sp * L2E * rsqrtf(l1);
    float mS = fmaxf(m1, 0.f);     // safe upper bound on p' = s*eff (eff <= 1)

    // P3: cum/effect + final exp2 + bf16 planes, all in one pass
    float l2 = 0.f;
    for (int c = 0; c < CD4; c += 2) {
      int jo = jb0 + 4 * c;
      char* base = (char*)(rowF + jo + 4 * (jo >> 5));
      f32x4 a = *(const f32x4*)base;
      f32x4 bq = *(const f32x4*)(base + 16);
      u16x8 hi8, lo8;
      #pragma unroll
      for (int e = 0; e < 8; ++e) {
        int jj = jo + e;
        float sv = (e < 4) ? a[e] : bq[e - 4];
        bool ok = jj <= jmax;
        float e1 = ok ? __builtin_amdgcn_exp2f(sv - m1) : 0.f;
        cum += e1;
        float rem = fmaxf(l1 - cum, 0.f);
        float dsq = sqrtf(rem * fabsf((float)(i - jj)));
        float eff = fmaxf(__builtin_amdgcn_exp2f(gmr * dsq), 1e-5f);
        float ev = ok ? __builtin_amdgcn_exp2f(sv * eff - mS) : 0.f;
        l2 += ev;
        __bf16 hb = (__bf16)ev;
        hi8[e] = __builtin_bit_cast(unsigned short, hb);
        lo8[e] = __builtin_bit_cast(unsigned short, (__bf16)(ev - (float)hb));
      }
      *(u16x8*)base = hi8;
      *(u16x8*)(base + 16) = lo8;
    }
    #pragma unroll
    for (int o = 16; o > 0; o >>= 1) l2 += __shfl_xor(l2, o, 32);
    bool validrow = (jmax >= 0) && !(ZP && i == 0);
    float wgt = validrow ? (1.f / l2) : 0.f;
    if (l == 0) wrow[g] = wgt;
  }
  __syncthreads();

  // ---- PV: wave owns (d-block, tile-parity); planes at 4*(jo+4*(jo>>5)) ----
  const int dblk = (DV == 64) ? (w & 3) : (w & 1);
  const int par  = (DV == 64) ? (w >> 2) : (w >> 1);
  const int dcol = h * DV + dblk * 16 + (lane & 15);
  const unsigned short* vrow = Vt + (size_t)dcol * MT + rowbase;
  f32x4 acco = {};
  const float* rowF = sc + qr * RS;
  __builtin_amdgcn_s_setprio(1);
  for (int t0 = par * 64; t0 < NK; t0 += NPAR * 64) {
    #pragma unroll
    for (int ks = 0; ks < 2; ++ks) {
      int jo = t0 + ks * 32 + ko8;
      const char* base = (const char*)(rowF + jo + 4 * (jo >> 5));
      bfrag ph = *(const bfrag*)base;
      bfrag pl = *(const bfrag*)(base + 16);
      bfrag vf = *(const bfrag*)(vrow + jo);
      acco = __builtin_amdgcn_mfma_f32_16x16x32_bf16(pl, vf, acco, 0, 0, 0);
      acco = __builtin_amdgcn_mfma_f32_16x16x32_bf16(ph, vf, acco, 0, 0, 0);
    }
  }
  __builtin_amdgcn_s_setprio(0);
  __syncthreads();                 // all plane reads complete; sc reusable

  float* redA = sc;                // alias partial-reduce buffer into sc
  if (w >= NFIN) {
    int slot = w - NFIN;
    #pragma unroll
    for (int q = 0; q < 4; ++q)
      redA[slot * 272 + ((lane >> 4) * 4 + q) * 17 + (lane & 15)] = acco[q];
  }
  __syncthreads();
  if (w < NFIN) {
    for (int pp = w; pp < NP; pp += NFIN) {
      #pragma unroll
      for (int q = 0; q < 4; ++q)
        acco[q] += redA[pp * 272 + ((lane >> 4) * 4 + q) * 17 + (lane & 15)];
    }
    int r0 = (lane >> 4) * 4;
    #pragma unroll
    for (int q = 0; q < 4; ++q) {
      float wv = wrow[r0 + q];
      O[(rowbase + i0 + r0 + q) * DMV + dcol] = f2bf(acco[q] * wv);
    }
  }
}

// ---------------- LayerNorm v4: one row per wave, float4 loads ----------------
template<int D, bool WF, bool WB>
__global__ __launch_bounds__(256) void ln4_kernel(
    const float* __restrict__ X, const float* __restrict__ R,
    const float* __restrict__ g, const float* __restrict__ be,
    float* __restrict__ Y, unsigned short* __restrict__ Yb)
{
  constexpr int NC = D / 256;
  int row = blockIdx.x * 4 + (threadIdx.x >> 6);
  int lane = threadIdx.x & 63;
  const float* x = X + (size_t)row * D;
  f32x4 xv[NC];
  float s = 0.f;
  #pragma unroll
  for (int c = 0; c < NC; ++c) {
    xv[c] = *(const f32x4*)(x + c * 256 + lane * 4);
    if (R) {
      f32x4 rv = *(const f32x4*)(R + (size_t)row * D + c * 256 + lane * 4);
      #pragma unroll
      for (int k = 0; k < 4; ++k) xv[c][k] += rv[k];
    }
    #pragma unroll
    for (int k = 0; k < 4; ++k) s += xv[c][k];
  }
  #pragma unroll
  for (int o = 32; o > 0; o >>= 1) s += __shfl_xor(s, o, 64);
  float mean = s / (float)D;
  float vs = 0.f;
  #pragma unroll
  for (int c = 0; c < NC; ++c)
    #pragma unroll
    for (int k = 0; k < 4; ++k) { float d = xv[c][k] - mean; vs += d * d; }
  #pragma unroll
  for (int o = 32; o > 0; o >>= 1) vs += __shfl_xor(vs, o, 64);
  float rstd = rsqrtf(vs / (float)D + 1e-5f);
  #pragma unroll
  for (int c = 0; c < NC; ++c) {
    f32x4 gv = *(const f32x4*)(g + c * 256 + lane * 4);
    f32x4 bv = *(const f32x4*)(be + c * 256 + lane * 4);
    f32x4 ov;
    #pragma unroll
    for (int k = 0; k < 4; ++k) ov[k] = gv[k] * (xv[c][k] - mean) * rstd + bv[k];
    if (WF) *(f32x4*)(Y + (size_t)row * D + c * 256 + lane * 4) = ov;
    if (WB) {
      ushort4 h4 = { f2bf(ov[0]), f2bf(ov[1]), f2bf(ov[2]), f2bf(ov[3]) };
      *(ushort4*)(Yb + (size_t)row * D + c * 256 + lane * 4) = h4;
    }
  }
}

// ---------------- fused concat + LN (D=512) ----------------
__global__ __launch_bounds__(256) void lnc_kernel(
    const float* __restrict__ Xh, const float* __restrict__ Qe,
    const float* __restrict__ g, const float* __restrict__ be,
    unsigned short* __restrict__ Yb)
{
  int row = blockIdx.x * 4 + (threadIdx.x >> 6);
  int lane = threadIdx.x & 63;
  f32x4 xv[2];
  xv[0] = *(const f32x4*)(Xh + (size_t)row * 256 + lane * 4);
  xv[1] = *(const f32x4*)(Qe + (size_t)row * 256 + lane * 4);
  float s = 0.f;
  #pragma unroll
  for (int c = 0; c < 2; ++c)
    #pragma unroll
    for (int k = 0; k < 4; ++k) s += xv[c][k];
  #pragma unroll
  for (int o = 32; o > 0; o >>= 1) s += __shfl_xor(s, o, 64);
  float mean = s / 512.f;
  float vs = 0.f;
  #pragma unroll
  for (int c = 0; c < 2; ++c)
    #pragma unroll
    for (int k = 0; k < 4; ++k) { float d = xv[c][k] - mean; vs += d * d; }
  #pragma unroll
  for (int o = 32; o > 0; o >>= 1) vs += __shfl_xor(vs, o, 64);
  float rstd = rsqrtf(vs / 512.f + 1e-5f);
  #pragma unroll
  for (int c = 0; c < 2; ++c) {
    f32x4 gv = *(const f32x4*)(g + c * 256 + lane * 4);
    f32x4 bv = *(const f32x4*)(be + c * 256 + lane * 4);
    ushort4 h4;
    #pragma unroll
    for (int k = 0; k < 4; ++k) {
      float ov = gv[k] * (xv[c][k] - mean) * rstd + bv[k];
      ((unsigned short*)&h4)[k] = f2bf(ov);
    }
    *(ushort4*)(Yb + (size_t)row * 512 + c * 256 + lane * 4) = h4;
  }
}

// ---------------- fused LN(D=256) + dot ----------------
__global__ __launch_bounds__(256) void lndot_kernel(
    const float* __restrict__ X, const float* __restrict__ g,
    const float* __restrict__ be, const float* __restrict__ w3,
    const float* __restrict__ b3, float* __restrict__ out)
{
  int row = blockIdx.x * 4 + (threadIdx.x >> 6);
  int lane = threadIdx.x & 63;
  f32x4 v = *(const f32x4*)(X + (size_t)row * 256 + lane * 4);
  float s = v[0] + v[1] + v[2] + v[3];
  #pragma unroll
  for (int o = 32; o > 0; o >>= 1) s += __shfl_xor(s, o, 64);
  float mean = s / 256.f;
  float vs = 0.f;
  #pragma unroll
  for (int k = 0; k < 4; ++k) { float d = v[k] - mean; vs += d * d; }
  #pragma unroll
  for (int o = 32; o > 0; o >>= 1) vs += __shfl_xor(vs, o, 64);
  float rstd = rsqrtf(vs / 256.f + 1e-5f);
  f32x4 gv = *(const f32x4*)(g + lane * 4);
  f32x4 bv = *(const f32x4*)(be + lane * 4);
  f32x4 wv = *(const f32x4*)(w3 + lane * 4);
  float d = 0.f;
  #pragma unroll
  for (int k = 0; k < 4; ++k)
    d += (gv[k] * (v[k] - mean) * rstd + bv[k]) * wv[k];
  #pragma unroll
  for (int o = 32; o > 0; o >>= 1) d += __shfl_xor(d, o, 64);
  if (lane == 0) out[row] = d + b3[0];
}

// ---------------- launch ----------------
extern "C" void kernel_launch(void* const* d_in, const int* in_sizes, int n_in,
                              void* d_out, int out_size, void* d_ws, size_t ws_size,
                              hipStream_t stream) {
  const int* p_data  = (const int*)d_in[0];
  const int* pa_data = (const int*)d_in[1];
  const float* pemb_W = (const float*)d_in[3];
  const float* diff_W = (const float*)d_in[4];
  const float* qemb_W = (const float*)d_in[5];
  const float* qemb_b = (const float*)d_in[6];
  const float* y_kW = (const float*)d_in[7];   const float* y_kb = (const float*)d_in[8];
  const float* y_vW = (const float*)d_in[9];   const float* y_vb = (const float*)d_in[10];
  const float* y_oW = (const float*)d_in[11];  const float* y_ob = (const float*)d_in[12];
  const float* y_gam = (const float*)d_in[13];
  const float* y_ln1g = (const float*)d_in[14]; const float* y_ln1b = (const float*)d_in[15];
  const float* y_f1W = (const float*)d_in[16]; const float* y_f1b = (const float*)d_in[17];
  const float* y_f2W = (const float*)d_in[18]; const float* y_f2b = (const float*)d_in[19];
  const float* y_ln2g = (const float*)d_in[20]; const float* y_ln2b = (const float*)d_in[21];
  const float* x_kW = (const float*)d_in[22];  const float* x_kb = (const float*)d_in[23];
  const float* x_vW = (const float*)d_in[24];  const float* x_vb = (const float*)d_in[25];
  const float* x_oW = (const float*)d_in[26];  const float* x_ob = (const float*)d_in[27];
  const float* x_gam = (const float*)d_in[28];
  const float* x_ln1g = (const float*)d_in[29]; const float* x_ln1b = (const float*)d_in[30];
  const float* h_kW = (const float*)d_in[31];  const float* h_kb = (const float*)d_in[32];
  const float* h_vW = (const float*)d_in[33];  const float* h_vb = (const float*)d_in[34];
  const float* h_oW = (const float*)d_in[35];  const float* h_ob = (const float*)d_in[36];
  const float* h_gam = (const float*)d_in[37];
  const float* h_ln1g = (const float*)d_in[38]; const float* h_ln1b = (const float*)d_in[39];
  const float* h_f1W = (const float*)d_in[40]; const float* h_f1b = (const float*)d_in[41];
  const float* h_f2W = (const float*)d_in[42]; const float* h_f2b = (const float*)d_in[43];
  const float* h_ln2g = (const float*)d_in[44]; const float* h_ln2b = (const float*)d_in[45];
  const float* oln1g = (const float*)d_in[46]; const float* oln1b = (const float*)d_in[47];
  const float* o1W = (const float*)d_in[48];   const float* o1b = (const float*)d_in[49];
  const float* oln2g = (const float*)d_in[50]; const float* oln2b = (const float*)d_in[51];
  const float* o2W = (const float*)d_in[52];   const float* o2b = (const float*)d_in[53];
  const float* oln3g = (const float*)d_in[54]; const float* oln3b = (const float*)d_in[55];
  const float* o3W = (const float*)d_in[56];   const float* o3b = (const float*)d_in[57];

  float* out_f = (float*)d_out;

  const int B = 8, S = 1024, M = B * S;
  const int R = 4097, KQ = 1025, KQP = 1088;   // pad to multiple of 64

  float* ws = (float*)d_ws;
  size_t off = 0;
  auto alloc = [&](size_t nfloats) { size_t o = off; off += (nfloats + 255) & ~(size_t)255; return o; };
  auto allocs = [&](size_t nshorts) { return alloc((nshorts + 1) / 2); };

  size_t oE    = alloc((size_t)R * 256);
  size_t oSIGb = allocs((size_t)R * KQP);
  size_t oSSUM = alloc(R);
  size_t oQE   = alloc((size_t)M * 256);
  size_t oQEb  = allocs((size_t)M * 256);
  size_t oQA   = alloc((size_t)M * 512);
  size_t oQAb  = allocs((size_t)M * 512);
  size_t oYOb  = allocs((size_t)M * 512);
  size_t oXO   = alloc((size_t)M * 256);
  size_t oXOb  = allocs((size_t)M * 256);
  size_t oHO   = alloc((size_t)M * 256);
  size_t oS0   = alloc((size_t)M * 512);   // FFb arena (S0+S1)
  size_t oS1   = alloc((size_t)M * 512);
  size_t oS2b  = allocs((size_t)M * 512);
  size_t oS3   = alloc((size_t)M * 512);
  size_t oS4   = alloc((size_t)M * 512);
  size_t oSX   = alloc((size_t)M * 512);
  size_t oSXb  = allocs((size_t)M * 512);
  size_t oS0b  = allocs((size_t)M * 512);
  size_t oVt   = allocs((size_t)M * 512);
  size_t oWqe  = allocs((size_t)256 * KQP);
  size_t oWyk  = allocs((size_t)512 * 512);
  size_t oWyv  = allocs((size_t)512 * 512);
  size_t oWyo  = allocs((size_t)512 * 512);
  size_t oWyf1 = allocs((size_t)2048 * 512);
  size_t oWyf2 = allocs((size_t)512 * 2048);
  size_t oWxk  = allocs((size_t)256 * 256);
  size_t oWxv  = allocs((size_t)256 * 256);
  size_t oWxo  = allocs((size_t)256 * 256);
  size_t oWhk  = allocs((size_t)256 * 256);
  size_t oWhv  = allocs((size_t)512 * 512);
  size_t oWho  = allocs((size_t)256 * 512);
  size_t oWhf1 = allocs((size_t)2048 * 256);
  size_t oWhf2 = allocs((size_t)256 * 2048);
  size_t oWo1  = allocs((size_t)512 * 512);
  size_t oWo2  = allocs((size_t)256 * 512);
  (void)ws_size; (void)in_sizes; (void)n_in; (void)out_size;

  float* E    = ws + oE;
  unsigned short* SIGb = (unsigned short*)(ws + oSIGb);
  float* SSUM = ws + oSSUM;
  float* QE   = ws + oQE;   unsigned short* QEb = (unsigned short*)(ws + oQEb);
  float* QA   = ws + oQA;   unsigned short* QAb = (unsigned short*)(ws + oQAb);
  unsigned short* YOb = (unsigned short*)(ws + oYOb);
  float* XO   = ws + oXO;   unsigned short* XOb = (unsigned short*)(ws + oXOb);
  float* HO   = ws + oHO;
  float* S0   = ws + oS0;
  unsigned short* S2b = (unsigned short*)(ws + oS2b);
  float* S3   = ws + oS3;
  float* S4   = ws + oS4;
  float* SX   = ws + oSX;   unsigned short* SXb = (unsigned short*)(ws + oSXb);
  unsigned short* S0b = (unsigned short*)(ws + oS0b);
  unsigned short* Vt  = (unsigned short*)(ws + oVt);
  unsigned short* FFb = (unsigned short*)S0;

  unsigned short* Wqe  = (unsigned short*)(ws + oWqe);
  unsigned short* Wyk  = (unsigned short*)(ws + oWyk);
  unsigned short* Wyv  = (unsigned short*)(ws + oWyv);
  unsigned short* Wyo  = (unsigned short*)(ws + oWyo);
  unsigned short* Wyf1 = (unsigned short*)(ws + oWyf1);
  unsigned short* Wyf2 = (unsigned short*)(ws + oWyf2);
  unsigned short* Wxk  = (unsigned short*)(ws + oWxk);
  unsigned short* Wxv  = (unsigned short*)(ws + oWxv);
  unsigned short* Wxo  = (unsigned short*)(ws + oWxo);
  unsigned short* Whk  = (unsigned short*)(ws + oWhk);
  unsigned short* Whv  = (unsigned short*)(ws + oWhv);
  unsigned short* Who  = (unsigned short*)(ws + oWho);
  unsigned short* Whf1 = (unsigned short*)(ws + oWhf1);
  unsigned short* Whf2 = (unsigned short*)(ws + oWhf2);
  unsigned short* Wo1  = (unsigned short*)(ws + oWo1);
  unsigned short* Wo2  = (unsigned short*)(ws + oWo2);

  dim3 blk(256);
  int nElem512 = (8192 * 512 + 255) / 256;

  // ---- fused weight transposes ----
  {
    struct HD { const float* src; unsigned short* dst; int K, N, Kp; };
    const HD hd[16] = {
      {qemb_W, Wqe, KQ, 256, KQP},
      {y_kW, Wyk, 512, 512, 512}, {y_vW, Wyv, 512, 512, 512}, {y_oW, Wyo, 512, 512, 512},
      {y_f1W, Wyf1, 512, 2048, 512}, {y_f2W, Wyf2, 2048, 512, 2048},
      {x_kW, Wxk, 256, 256, 256}, {x_vW, Wxv, 256, 256, 256}, {x_oW, Wxo, 256, 256, 256},
      {h_kW, Whk, 256, 256, 256}, {h_vW, Whv, 512, 512, 512}, {h_oW, Who, 512, 256, 512},
      {h_f1W, Whf1, 256, 2048, 256}, {h_f2W, Whf2, 2048, 256, 2048},
      {o1W, Wo1, 512, 512, 512}, {o2W, Wo2, 512, 256, 512},
    };
    TPack P;
    int tot = 0;
    for (int k = 0; k < 16; ++k) {
      int tx = (hd[k].N + 31) / 32, ty = (hd[k].Kp + 31) / 32;
      P.d[k] = { hd[k].src, hd[k].dst, hd[k].K, hd[k].N, hd[k].Kp, tx, tot };
      tot += tx * ty;
    }
    tconv_all_kernel<<<dim3(tot), blk, 0, stream>>>(P);
  }

  auto gg = [](int BMv, int TNv, int Mm, int Nn) {
    return dim3((unsigned)(Nn / TNv), (unsigned)((Mm + BMv - 1) / BMv));
  };

  // 1. embedding table
  sig_kernel<<<R, blk, 0, stream>>>(pemb_W, SIGb, SSUM, KQ, KQP);
  mgemm_kernel<64, 64, 2, true, false, false><<<gg(64, 64, R, 256), blk, 0, stream>>>(SIGb, Wqe, qemb_b, E, nullptr, nullptr, R, 256, KQP, SSUM, nullptr, 0);
  gather_kernel<<<nElem512, blk, 0, stream>>>(p_data, pa_data, E, diff_W, QE, QEb, QA, QAb);
  creg_kernel<<<1, blk, 0, stream>>>(p_data, diff_W, out_f + 8192);

  dim3 ablk(512);
  dim3 lgrid(M / 4);
  dim3 agA(64, B * NHEADS);

  // 2. y layer (dm=512, mask_k=1, zero_pad=0, FFN). Fused KV proj.
  mgemm_kernel<128, 64, 0, false, true, true><<<gg(128, 64, M, 1024), blk, 0, stream>>>(QAb, Wyk, y_kb, nullptr, S0b, Vt, M, 1024, 512, nullptr, y_vb, 512);
  attnC_kernel<64, 64, 1, 0><<<agA, ablk, 0, stream>>>(S0b, Vt, y_gam, S2b, S, M);
  mgemm_kernel<128, 64, 0, true, false, false><<<gg(128, 64, M, 512), blk, 0, stream>>>(S2b, Wyo, y_ob, S3, nullptr, nullptr, M, 512, 512, nullptr, nullptr, 0);
  ln4_kernel<512, true, true><<<lgrid, blk, 0, stream>>>(QA, S3, y_ln1g, y_ln1b, SX, SXb);
  mgemm_kernel<128, 128, 1, false, true, false><<<gg(128, 128, M, 2048), blk, 0, stream>>>(SXb, Wyf1, y_f1b, nullptr, FFb, nullptr, M, 2048, 512, nullptr, nullptr, 0);
  mgemm_kernel<128, 64, 0, true, false, false><<<gg(128, 64, M, 512), blk, 0, stream>>>(FFb, Wyf2, y_f2b, S4, nullptr, nullptr, M, 512, 2048, nullptr, nullptr, 0);
  ln4_kernel<512, false, true><<<lgrid, blk, 0, stream>>>(SX, S4, y_ln2g, y_ln2b, nullptr, YOb);

  // 3. x layer (dm=256, mask_k=1, zero_pad=0, no FFN). Fused KV proj.
  mgemm_kernel<128, 64, 0, false, true, true><<<gg(128, 64, M, 512), blk, 0, stream>>>(QEb, Wxk, x_kb, nullptr, S0b, Vt, M, 512, 256, nullptr, x_vb, 256);
  attnC_kernel<32, 32, 1, 0><<<agA, ablk, 0, stream>>>(S0b, Vt, x_gam, S2b, S, M);
  mgemm_kernel<64, 64, 0, true, false, false><<<gg(64, 64, M, 256), blk, 0, stream>>>(S2b, Wxo, x_ob, S3, nullptr, nullptr, M, 256, 256, nullptr, nullptr, 0);
  ln4_kernel<256, true, true><<<lgrid, blk, 0, stream>>>(QE, S3, x_ln1g, x_ln1b, XO, XOb);

  // 4. h layer (q,k from XO; v from YO; mask_k=0, zero_pad=1, FFN)
  mgemm_kernel<64, 64, 0, false, true, false><<<gg(64, 64, M, 256), blk, 0, stream>>>(XOb, Whk, h_kb, nullptr, S0b, nullptr, M, 256, 256, nullptr, nullptr, 0);
  mgemm_kernel<128, 64, 0, false, false, true><<<gg(128, 64, M, 512), blk, 0, stream>>>(YOb, Whv, h_vb, nullptr, nullptr, Vt, M, 512, 512, nullptr, nullptr, 0);
  attnC_kernel<32, 64, 0, 1><<<agA, ablk, 0, stream>>>(S0b, Vt, h_gam, S2b, S, M);
  mgemm_kernel<64, 64, 0, true, false, false><<<gg(64, 64, M, 256), blk, 0, stream>>>(S2b, Who, h_ob, S3, nullptr, nullptr, M, 256, 512, nullptr, nullptr, 0);
  ln4_kernel<256, true, true><<<lgrid, blk, 0, stream>>>(XO, S3, h_ln1g, h_ln1b, SX, SXb);
  mgemm_kernel<128, 128, 1, false, true, false><<<gg(128, 128, M, 2048), blk, 0, stream>>>(SXb, Whf1, h_f1b, nullptr, FFb, nullptr, M, 2048, 256, nullptr, nullptr, 0);
  mgemm_kernel<64, 64, 0, true, false, false><<<gg(64, 64, M, 256), blk, 0, stream>>>(FFb, Whf2, h_f2b, S4, nullptr, nullptr, M, 256, 2048, nullptr, nullptr, 0);
  ln4_kernel<256, true, false><<<lgrid, blk, 0, stream>>>(SX, S4, h_ln2g, h_ln2b, HO, nullptr);

  // 5. head: LN(concat) -> o1 -> LN -> o2 -> LN+dot
  lnc_kernel<<<lgrid, blk, 0, stream>>>(HO, QE, oln1g, oln1b, SXb);
  mgemm_kernel<128, 64, 1, true, false, false><<<gg(128, 64, M, 512), blk, 0, stream>>>(SXb, Wo1, o1b, S3, nullptr, nullptr, M, 512, 512, nullptr, nullptr, 0);
  ln4_kernel<512, false, true><<<lgrid, blk, 0, stream>>>(S3, nullptr, oln2g, oln2b, nullptr, SXb);
  mgemm_kernel<64, 64, 1, true, false, false><<<gg(64, 64, M, 256), blk, 0, stream>>>(SXb, Wo2, o2b, S4, nullptr, nullptr, M, 256, 512, nullptr, nullptr, 0);
  lndot_kernel<<<lgrid, blk, 0, stream>>>(S4, oln3g, oln3b, o3W, o3b, out_f);
}

// Round 19
// 681.310 us; speedup vs baseline: 1.0598x; 1.0377x over previous
//
#include <hip/hip_runtime.h>
#include <hip/hip_bf16.h>
#include <math.h>

#define NHEADS 8
#define L2E 1.44269504f

typedef __attribute__((ext_vector_type(8))) __bf16 bfrag;
typedef __attribute__((ext_vector_type(4))) float f32x4;
typedef __attribute__((ext_vector_type(8))) unsigned short u16x8;

static __device__ __forceinline__ unsigned short f2bf(float f) {
  unsigned u = __float_as_uint(f);
  unsigned r = (u + 0x7fffu + ((u >> 16) & 1u)) >> 16;
  return (unsigned short)r;
}

static __device__ __forceinline__ void gload_lds16(const void* g, void* l) {
  __builtin_amdgcn_global_load_lds(
      (const __attribute__((address_space(1))) unsigned int*)g,
      (__attribute__((address_space(3))) unsigned int*)l, 16, 0, 0);
}

static __device__ __forceinline__ float block_reduce_sum(float v, float* red) {
  int t = threadIdx.x;
  red[t] = v; __syncthreads();
  for (int s = 128; s > 0; s >>= 1) {
    if (t < s) red[t] += red[t + s];
    __syncthreads();
  }
  float r = red[0];
  __syncthreads();
  return r;
}

// ---------------- sigmoid table (bf16, padded to Kp) + row sums ----------------
__global__ __launch_bounds__(256) void sig_kernel(
    const float* __restrict__ Wp, unsigned short* __restrict__ Sgb,
    float* __restrict__ Ssum, int Kd, int Kp)
{
  __shared__ float red[256];
  int row = blockIdx.x;
  float s = 0.f;
  for (int k = threadIdx.x; k < Kp; k += 256) {
    float v = 0.f;
    if (k < Kd) {
      v = 1.f / (1.f + __expf(-Wp[(size_t)row * Kd + k]));
      s += v;
    }
    Sgb[(size_t)row * Kp + k] = f2bf(v);
  }
  float tot = block_reduce_sum(s, red);
  if (threadIdx.x == 0) Ssum[row] = tot;
}

// ---------------- fused transpose+convert for all weights ----------------
struct TDesc { const float* src; unsigned short* dst; int K, N, Kp, tilesX, blk0; };
struct TPack { TDesc d[16]; };

__global__ __launch_bounds__(256) void tconv_all_kernel(TPack P) {
  __shared__ float t[32][33];
  int bid = blockIdx.x;
  int di = 0;
  #pragma unroll
  for (int k = 1; k < 16; ++k) if (bid >= P.d[k].blk0) di = k;
  const float* src = P.d[di].src;
  unsigned short* dst = P.d[di].dst;
  int K = P.d[di].K, N = P.d[di].N, Kp = P.d[di].Kp, tilesX = P.d[di].tilesX;
  int local = bid - P.d[di].blk0;
  int bn = (local % tilesX) * 32;
  int bk = (local / tilesX) * 32;
  int tid = threadIdx.x;
  int tx = tid & 31, ty = tid >> 5;
  #pragma unroll
  for (int u = 0; u < 4; ++u) {
    int k = bk + ty + u * 8, n = bn + tx;
    t[ty + u * 8][tx] = (k < K && n < N) ? src[(size_t)k * N + n] : 0.f;
  }
  __syncthreads();
  #pragma unroll
  for (int u = 0; u < 4; ++u) {
    int n = bn + ty + u * 8, kk = bk + tx;
    if (n < N && kk < Kp)
      dst[(size_t)n * Kp + kk] = f2bf(t[tx][ty + u * 8]);
  }
}

// ---------------- MFMA bf16 GEMM: C = epi(A @ Bt^T + bias), BK=64 ----------------
// Tiles: (BM,TN) in {(128,128),(128,64),(64,64)}. 4 waves = 2x2.
// Rows are 64 bf16 = 128B = 8 granules; swizzle involution gs = g ^ (r&7).
// XCD-chunked bijective blockIdx swizzle (m204) for per-XCD L2 panel reuse.
template<int BM, int TN, int EPI, bool WF32, bool WBF, bool WTR>
__global__ __launch_bounds__(256) void mgemm_kernel(
    const unsigned short* __restrict__ A, const unsigned short* __restrict__ Bt,
    const float* __restrict__ bias, float* __restrict__ C,
    unsigned short* __restrict__ Cb, unsigned short* __restrict__ Ct,
    int M, int N, int K, const float* __restrict__ divv,
    const float* __restrict__ bias2, int Nk)
{
  constexpr int NI = BM / 32, NJ = TN / 32;
  constexpr int WR = BM / 2, WC = TN / 2;
  constexpr int APASS = BM / 32, BPASS = TN / 32;   // staging passes (4KB each)
  constexpr bool SPLIT = WBF && WTR;
  __shared__ __align__(16) unsigned short Als[BM * 64];
  __shared__ __align__(16) unsigned short Bls[TN * 64];
  const int tid = threadIdx.x;
  const int lane = tid & 63, w = tid >> 6;
  const int wm = w >> 1, wn = w & 1;

  // XCD-chunked bijective block swizzle
  const int nwg = gridDim.x * gridDim.y;
  const int orig = blockIdx.y * gridDim.x + blockIdx.x;
  const int qq = nwg >> 3, rr = nwg & 7;
  const int xcd = orig & 7, idx = orig >> 3;
  const int Wz = (xcd < rr ? xcd * (qq + 1) : rr * (qq + 1) + (xcd - rr) * qq) + idx;
  const int bxs = Wz % gridDim.x, bys = Wz / gridDim.x;
  const int brow = bys * BM, bcol = bxs * TN;

  f32x4 acc[NI][NJ] = {};

  for (int k0 = 0; k0 < K; k0 += 64) {
    #pragma unroll
    for (int q = 0; q < BPASS; ++q) {
      int s = q * 256 + tid;
      int r = s >> 3, g = s & 7;
      int gs = g ^ (r & 7);
      int gc = bcol + r; if (gc > N - 1) gc = N - 1;
      gload_lds16(Bt + (size_t)gc * K + k0 + gs * 8,
                  (char*)Bls + (q * 4096 + w * 1024));
    }
    #pragma unroll
    for (int q = 0; q < APASS; ++q) {
      int s = q * 256 + tid;
      int r = s >> 3, g = s & 7;
      int gs = g ^ (r & 7);
      int gr = brow + r; if (gr > M - 1) gr = M - 1;
      gload_lds16(A + (size_t)gr * K + k0 + gs * 8,
                  (char*)Als + (q * 4096 + w * 1024));
    }
    __syncthreads();

    #pragma unroll
    for (int ks = 0; ks < 2; ++ks) {
      bfrag av[NI], bv[NJ];
      #pragma unroll
      for (int f = 0; f < NI; ++f) {
        int rA = wm * WR + f * 16 + (lane & 15);
        int gsl = (ks * 4 + (lane >> 4)) ^ (rA & 7);
        av[f] = *(const bfrag*)((const char*)Als + rA * 128 + gsl * 16);
      }
      #pragma unroll
      for (int f = 0; f < NJ; ++f) {
        int rB = wn * WC + f * 16 + (lane & 15);
        int gsl = (ks * 4 + (lane >> 4)) ^ (rB & 7);
        bv[f] = *(const bfrag*)((const char*)Bls + rB * 128 + gsl * 16);
      }
      #pragma unroll
      for (int i = 0; i < NI; ++i)
        #pragma unroll
        for (int j = 0; j < NJ; ++j)
          acc[i][j] = __builtin_amdgcn_mfma_f32_16x16x32_bf16(av[i], bv[j], acc[i][j], 0, 0, 0);
    }
    __syncthreads();
  }

  #pragma unroll
  for (int i = 0; i < NI; ++i) {
    int gr0 = brow + wm * WR + i * 16 + (lane >> 4) * 4;
    #pragma unroll
    for (int j = 0; j < NJ; ++j) {
      int gc = bcol + wn * WC + j * 16 + (lane & 15);
      float bsv;
      if (SPLIT) bsv = (gc < Nk) ? bias[gc] : bias2[gc - Nk];
      else       bsv = bias ? bias[gc] : 0.f;
      float vv[4];
      #pragma unroll
      for (int q = 0; q < 4; ++q) {
        int gr = gr0 + q;
        float v = acc[i][j][q] + bsv;
        if (EPI >= 1) v = fmaxf(v, 0.f);
        if (EPI == 2) v = (gr < M) ? v / divv[gr] : v;
        vv[q] = v;
      }
      if (SPLIT) {
        if (gc < Nk) {
          #pragma unroll
          for (int q = 0; q < 4; ++q) {
            int gr = gr0 + q;
            if (gr < M) Cb[(size_t)gr * Nk + gc] = f2bf(vv[q]);
          }
        } else {
          ushort4 h4 = { f2bf(vv[0]), f2bf(vv[1]), f2bf(vv[2]), f2bf(vv[3]) };
          *(ushort4*)(Ct + (size_t)(gc - Nk) * M + gr0) = h4;
        }
      } else {
        #pragma unroll
        for (int q = 0; q < 4; ++q) {
          int gr = gr0 + q;
          if (gr >= M) continue;
          if (WF32) C[(size_t)gr * N + gc] = vv[q];
          if (WBF)  Cb[(size_t)gr * N + gc] = f2bf(vv[q]);
        }
        if (WTR) {
          ushort4 h4 = { f2bf(vv[0]), f2bf(vv[1]), f2bf(vv[2]), f2bf(vv[3]) };
          *(ushort4*)(Ct + (size_t)gc * M + gr0) = h4;
        }
      }
    }
  }
}

// ---------------- embedding gather ----------------
__global__ __launch_bounds__(256) void gather_kernel(
    const int* __restrict__ p_data, const int* __restrict__ pa_data,
    const float* __restrict__ E, const float* __restrict__ diff_W,
    float* __restrict__ qemb, unsigned short* __restrict__ qembb,
    float* __restrict__ qaemb, unsigned short* __restrict__ qaembb)
{
  int idx = blockIdx.x * 256 + threadIdx.x;
  if (idx >= 8192 * 512) return;
  int row = idx >> 9, c = idx & 511;
  int p = p_data[row];
  float pid = diff_W[p];
  if (c < 256) {
    float v = E[(size_t)p * 256 + c] + pid;
    qemb[(size_t)row * 256 + c] = v;
    qembb[(size_t)row * 256 + c] = f2bf(v);
  }
  int pa = pa_data[row];
  int ppos = (pa > 4096) ? pa - 4096 : 0;
  int pneg = (pa <= 4096) ? pa : 0;
  float v = (c < 256) ? E[(size_t)ppos * 256 + c] : E[(size_t)pneg * 256 + (c - 256)];
  v += pid;
  qaemb[(size_t)row * 512 + c] = v;
  qaembb[(size_t)row * 512 + c] = f2bf(v);
}

// ---------------- c_reg ----------------
__global__ __launch_bounds__(256) void creg_kernel(
    const int* __restrict__ p_data, const float* __restrict__ dW,
    float* __restrict__ out)
{
  __shared__ float red[256];
  float s = 0.f;
  for (int i = threadIdx.x; i < 8192; i += 256) {
    float v = dW[p_data[i]];
    s += v * v;
  }
  float tot = block_reduce_sum(s, red);
  if (threadIdx.x == 0) out[0] = tot * 1e-5f;
}

// ---------------- MFMA distance-decay attention v14: 3-pass streaming softmax ----------------
template<int DK, int DV, int MASKK, int ZP>
__global__ __launch_bounds__(512, 4) void attnC_kernel(
    const unsigned short* __restrict__ QKb, const unsigned short* __restrict__ Vt,
    const float* __restrict__ gamp, unsigned short* __restrict__ O,
    int S, int MT)
{
  constexpr int RS = 1156;
  constexpr int NPAR = (DV == 64) ? 2 : 4;
  constexpr int NFIN = (DV == 64) ? 4 : 2;
  constexpr int NP   = (DV == 32) ? 6 : 4;
  const int DMK = NHEADS * DK, DMV = NHEADS * DV;
  const int id = blockIdx.x + blockIdx.y * 64;
  const int W = (id & 7) * 512 + (id >> 3);     // XCD-chunked bijection (4096 blocks)
  const int ib = 63 - (W & 63);                 // descending-NK order
  const int bh = W >> 6;
  const int i0 = ib * 16;
  const int b = bh >> 3, h = bh & 7;
  const int tid = threadIdx.x;
  const int lane = tid & 63, w = tid >> 6;
  const size_t rowbase = (size_t)b * S;

  __shared__ __align__(16) float sc[16 * RS];
  __shared__ float wrow[16];

  const int jmaxBlk = MASKK ? (i0 + 15) : (i0 + 14);
  const int NK = (jmaxBlk / 64 + 1) * 64;
  const int NKp = (NK + 255) & ~255;            // 256..1024
  const int CD = NKp >> 5;                      // 8,16,24,32 elems/lane

  const int qr = lane & 15;
  const int ko8 = (lane >> 4) * 8;
  const float rscale = rsqrtf((float)DK) * L2E;

  bfrag qf[DK / 32];
  #pragma unroll
  for (int ks = 0; ks < DK / 32; ++ks)
    qf[ks] = *(const bfrag*)(QKb + (rowbase + i0 + qr) * DMK + h * DK + ks * 32 + ko8);

  // ---- QK^T (rscale*L2E folded into scatter) ----
  for (int t0 = 0; t0 < NK; t0 += 128) {
    int tt = t0 + (w >> 2) * 64;
    if (tt < NK) {
      int jb = tt + (w & 3) * 16 + qr;
      bfrag kf[DK / 32];
      #pragma unroll
      for (int ks = 0; ks < DK / 32; ++ks)
        kf[ks] = *(const bfrag*)(QKb + (rowbase + jb) * DMK + h * DK + ks * 32 + ko8);
      f32x4 accs = {};
      __builtin_amdgcn_s_setprio(1);
      #pragma unroll
      for (int ks = 0; ks < DK / 32; ++ks)
        accs = __builtin_amdgcn_mfma_f32_16x16x32_bf16(qf[ks], kf[ks], accs, 0, 0, 0);
      __builtin_amdgcn_s_setprio(0);
      int ja = jb + 4 * (jb >> 5);
      int r0 = (lane >> 4) * 4;
      #pragma unroll
      for (int q = 0; q < 4; ++q)
        sc[(r0 + q) * RS + ja] = accs[q] * rscale;
    }
  }
  __syncthreads();

  // ---- streaming softmax (exp2 domain), 3 passes ----
  {
    const int g = tid >> 5, l = tid & 31;
    const int i = i0 + g;
    const int jmax = MASKK ? i : i - 1;
    const int jb0 = CD * l;
    const int CD4 = CD >> 2;
    float* rowF = sc + g * RS;

    // P1: max
    float m1 = -1e30f;
    for (int c = 0; c < CD4; ++c) {
      int j = jb0 + 4 * c;
      f32x4 v = *(const f32x4*)(rowF + j + 4 * (j >> 5));
      #pragma unroll
      for (int k = 0; k < 4; ++k)
        m1 = fmaxf(m1, (j + k <= jmax) ? v[k] : -1e30f);
    }
    #pragma unroll
    for (int o = 16; o > 0; o >>= 1) m1 = fmaxf(m1, __shfl_xor(m1, o, 32));

    // P2: lane-local sum of exp2
    float lloc = 0.f;
    for (int c = 0; c < CD4; ++c) {
      int j = jb0 + 4 * c;
      f32x4 v = *(const f32x4*)(rowF + j + 4 * (j >> 5));
      #pragma unroll
      for (int k = 0; k < 4; ++k)
        lloc += (j + k <= jmax) ? __builtin_amdgcn_exp2f(v[k] - m1) : 0.f;
    }
    float l1 = lloc;
    #pragma unroll
    for (int o = 16; o > 0; o >>= 1) l1 += __shfl_xor(l1, o, 32);

    float scn = lloc;
    #pragma unroll
    for (int o = 1; o < 32; o <<= 1) {
      float u = __shfl_up(scn, o, 32);
      if (l >= o) scn += u;
    }
    float cum = scn - lloc;

    float gv = gamp[h];
    float sp = fmaxf(gv, 0.f) + log1pf(__expf(-fabsf(gv)));
    float gmr = -sp * L2E * rsqrtf(l1);
    float mS = fmaxf(m1, 0.f);     // safe upper bound on p' = s*eff (eff <= 1)

    // P3: cum/effect + final exp2 + bf16 planes, all in one pass
    float l2 = 0.f;
    for (int c = 0; c < CD4; c += 2) {
      int jo = jb0 + 4 * c;
      char* base = (char*)(rowF + jo + 4 * (jo >> 5));
      f32x4 a = *(const f32x4*)base;
      f32x4 bq = *(const f32x4*)(base + 16);
      u16x8 hi8, lo8;
      #pragma unroll
      for (int e = 0; e < 8; ++e) {
        int jj = jo + e;
        float sv = (e < 4) ? a[e] : bq[e - 4];
        bool ok = jj <= jmax;
        float e1 = ok ? __builtin_amdgcn_exp2f(sv - m1) : 0.f;
        cum += e1;
        float rem = fmaxf(l1 - cum, 0.f);
        float dsq = sqrtf(rem * fabsf((float)(i - jj)));
        float eff = fmaxf(__builtin_amdgcn_exp2f(gmr * dsq), 1e-5f);
        float ev = ok ? __builtin_amdgcn_exp2f(sv * eff - mS) : 0.f;
        l2 += ev;
        __bf16 hb = (__bf16)ev;
        hi8[e] = __builtin_bit_cast(unsigned short, hb);
        lo8[e] = __builtin_bit_cast(unsigned short, (__bf16)(ev - (float)hb));
      }
      *(u16x8*)base = hi8;
      *(u16x8*)(base + 16) = lo8;
    }
    #pragma unroll
    for (int o = 16; o > 0; o >>= 1) l2 += __shfl_xor(l2, o, 32);
    bool validrow = (jmax >= 0) && !(ZP && i == 0);
    float wgt = validrow ? (1.f / l2) : 0.f;
    if (l == 0) wrow[g] = wgt;
  }
  __syncthreads();

  // ---- PV: wave owns (d-block, tile-parity); planes at 4*(jo+4*(jo>>5)) ----
  const int dblk = (DV == 64) ? (w & 3) : (w & 1);
  const int par  = (DV == 64) ? (w >> 2) : (w >> 1);
  const int dcol = h * DV + dblk * 16 + (lane & 15);
  const unsigned short* vrow = Vt + (size_t)dcol * MT + rowbase;
  f32x4 acco = {};
  const float* rowF = sc + qr * RS;
  __builtin_amdgcn_s_setprio(1);
  for (int t0 = par * 64; t0 < NK; t0 += NPAR * 64) {
    #pragma unroll
    for (int ks = 0; ks < 2; ++ks) {
      int jo = t0 + ks * 32 + ko8;
      const char* base = (const char*)(rowF + jo + 4 * (jo >> 5));
      bfrag ph = *(const bfrag*)base;
      bfrag pl = *(const bfrag*)(base + 16);
      bfrag vf = *(const bfrag*)(vrow + jo);
      acco = __builtin_amdgcn_mfma_f32_16x16x32_bf16(pl, vf, acco, 0, 0, 0);
      acco = __builtin_amdgcn_mfma_f32_16x16x32_bf16(ph, vf, acco, 0, 0, 0);
    }
  }
  __builtin_amdgcn_s_setprio(0);
  __syncthreads();                 // all plane reads complete; sc reusable

  float* redA = sc;                // alias partial-reduce buffer into sc
  if (w >= NFIN) {
    int slot = w - NFIN;
    #pragma unroll
    for (int q = 0; q < 4; ++q)
      redA[slot * 272 + ((lane >> 4) * 4 + q) * 17 + (lane & 15)] = acco[q];
  }
  __syncthreads();
  if (w < NFIN) {
    for (int pp = w; pp < NP; pp += NFIN) {
      #pragma unroll
      for (int q = 0; q < 4; ++q)
        acco[q] += redA[pp * 272 + ((lane >> 4) * 4 + q) * 17 + (lane & 15)];
    }
    int r0 = (lane >> 4) * 4;
    #pragma unroll
    for (int q = 0; q < 4; ++q) {
      float wv = wrow[r0 + q];
      O[(rowbase + i0 + r0 + q) * DMV + dcol] = f2bf(acco[q] * wv);
    }
  }
}

// ---------------- LayerNorm v4: one row per wave, float4 loads ----------------
template<int D, bool WF, bool WB>
__global__ __launch_bounds__(256) void ln4_kernel(
    const float* __restrict__ X, const float* __restrict__ R,
    const float* __restrict__ g, const float* __restrict__ be,
    float* __restrict__ Y, unsigned short* __restrict__ Yb)
{
  constexpr int NC = D / 256;
  int row = blockIdx.x * 4 + (threadIdx.x >> 6);
  int lane = threadIdx.x & 63;
  const float* x = X + (size_t)row * D;
  f32x4 xv[NC];
  float s = 0.f;
  #pragma unroll
  for (int c = 0; c < NC; ++c) {
    xv[c] = *(const f32x4*)(x + c * 256 + lane * 4);
    if (R) {
      f32x4 rv = *(const f32x4*)(R + (size_t)row * D + c * 256 + lane * 4);
      #pragma unroll
      for (int k = 0; k < 4; ++k) xv[c][k] += rv[k];
    }
    #pragma unroll
    for (int k = 0; k < 4; ++k) s += xv[c][k];
  }
  #pragma unroll
  for (int o = 32; o > 0; o >>= 1) s += __shfl_xor(s, o, 64);
  float mean = s / (float)D;
  float vs = 0.f;
  #pragma unroll
  for (int c = 0; c < NC; ++c)
    #pragma unroll
    for (int k = 0; k < 4; ++k) { float d = xv[c][k] - mean; vs += d * d; }
  #pragma unroll
  for (int o = 32; o > 0; o >>= 1) vs += __shfl_xor(vs, o, 64);
  float rstd = rsqrtf(vs / (float)D + 1e-5f);
  #pragma unroll
  for (int c = 0; c < NC; ++c) {
    f32x4 gv = *(const f32x4*)(g + c * 256 + lane * 4);
    f32x4 bv = *(const f32x4*)(be + c * 256 + lane * 4);
    f32x4 ov;
    #pragma unroll
    for (int k = 0; k < 4; ++k) ov[k] = gv[k] * (xv[c][k] - mean) * rstd + bv[k];
    if (WF) *(f32x4*)(Y + (size_t)row * D + c * 256 + lane * 4) = ov;
    if (WB) {
      ushort4 h4 = { f2bf(ov[0]), f2bf(ov[1]), f2bf(ov[2]), f2bf(ov[3]) };
      *(ushort4*)(Yb + (size_t)row * D + c * 256 + lane * 4) = h4;
    }
  }
}

// ---------------- fused concat + LN (D=512) ----------------
__global__ __launch_bounds__(256) void lnc_kernel(
    const float* __restrict__ Xh, const float* __restrict__ Qe,
    const float* __restrict__ g, const float* __restrict__ be,
    unsigned short* __restrict__ Yb)
{
  int row = blockIdx.x * 4 + (threadIdx.x >> 6);
  int lane = threadIdx.x & 63;
  f32x4 xv[2];
  xv[0] = *(const f32x4*)(Xh + (size_t)row * 256 + lane * 4);
  xv[1] = *(const f32x4*)(Qe + (size_t)row * 256 + lane * 4);
  float s = 0.f;
  #pragma unroll
  for (int c = 0; c < 2; ++c)
    #pragma unroll
    for (int k = 0; k < 4; ++k) s += xv[c][k];
  #pragma unroll
  for (int o = 32; o > 0; o >>= 1) s += __shfl_xor(s, o, 64);
  float mean = s / 512.f;
  float vs = 0.f;
  #pragma unroll
  for (int c = 0; c < 2; ++c)
    #pragma unroll
    for (int k = 0; k < 4; ++k) { float d = xv[c][k] - mean; vs += d * d; }
  #pragma unroll
  for (int o = 32; o > 0; o >>= 1) vs += __shfl_xor(vs, o, 64);
  float rstd = rsqrtf(vs / 512.f + 1e-5f);
  #pragma unroll
  for (int c = 0; c < 2; ++c) {
    f32x4 gv = *(const f32x4*)(g + c * 256 + lane * 4);
    f32x4 bv = *(const f32x4*)(be + c * 256 + lane * 4);
    ushort4 h4;
    #pragma unroll
    for (int k = 0; k < 4; ++k) {
      float ov = gv[k] * (xv[c][k] - mean) * rstd + bv[k];
      ((unsigned short*)&h4)[k] = f2bf(ov);
    }
    *(ushort4*)(Yb + (size_t)row * 512 + c * 256 + lane * 4) = h4;
  }
}

// ---------------- fused LN(D=256) + dot ----------------
__global__ __launch_bounds__(256) void lndot_kernel(
    const float* __restrict__ X, const float* __restrict__ g,
    const float* __restrict__ be, const float* __restrict__ w3,
    const float* __restrict__ b3, float* __restrict__ out)
{
  int row = blockIdx.x * 4 + (threadIdx.x >> 6);
  int lane = threadIdx.x & 63;
  f32x4 v = *(const f32x4*)(X + (size_t)row * 256 + lane * 4);
  float s = v[0] + v[1] + v[2] + v[3];
  #pragma unroll
  for (int o = 32; o > 0; o >>= 1) s += __shfl_xor(s, o, 64);
  float mean = s / 256.f;
  float vs = 0.f;
  #pragma unroll
  for (int k = 0; k < 4; ++k) { float d = v[k] - mean; vs += d * d; }
  #pragma unroll
  for (int o = 32; o > 0; o >>= 1) vs += __shfl_xor(vs, o, 64);
  float rstd = rsqrtf(vs / 256.f + 1e-5f);
  f32x4 gv = *(const f32x4*)(g + lane * 4);
  f32x4 bv = *(const f32x4*)(be + lane * 4);
  f32x4 wv = *(const f32x4*)(w3 + lane * 4);
  float d = 0.f;
  #pragma unroll
  for (int k = 0; k < 4; ++k)
    d += (gv[k] * (v[k] - mean) * rstd + bv[k]) * wv[k];
  #pragma unroll
  for (int o = 32; o > 0; o >>= 1) d += __shfl_xor(d, o, 64);
  if (lane == 0) out[row] = d + b3[0];
}

// ---------------- launch ----------------
extern "C" void kernel_launch(void* const* d_in, const int* in_sizes, int n_in,
                              void* d_out, int out_size, void* d_ws, size_t ws_size,
                              hipStream_t stream) {
  const int* p_data  = (const int*)d_in[0];
  const int* pa_data = (const int*)d_in[1];
  const float* pemb_W = (const float*)d_in[3];
  const float* diff_W = (const float*)d_in[4];
  const float* qemb_W = (const float*)d_in[5];
  const float* qemb_b = (const float*)d_in[6];
  const float* y_kW = (const float*)d_in[7];   const float* y_kb = (const float*)d_in[8];
  const float* y_vW = (const float*)d_in[9];   const float* y_vb = (const float*)d_in[10];
  const float* y_oW = (const float*)d_in[11];  const float* y_ob = (const float*)d_in[12];
  const float* y_gam = (const float*)d_in[13];
  const float* y_ln1g = (const float*)d_in[14]; const float* y_ln1b = (const float*)d_in[15];
  const float* y_f1W = (const float*)d_in[16]; const float* y_f1b = (const float*)d_in[17];
  const float* y_f2W = (const float*)d_in[18]; const float* y_f2b = (const float*)d_in[19];
  const float* y_ln2g = (const float*)d_in[20]; const float* y_ln2b = (const float*)d_in[21];
  const float* x_kW = (const float*)d_in[22];  const float* x_kb = (const float*)d_in[23];
  const float* x_vW = (const float*)d_in[24];  const float* x_vb = (const float*)d_in[25];
  const float* x_oW = (const float*)d_in[26];  const float* x_ob = (const float*)d_in[27];
  const float* x_gam = (const float*)d_in[28];
  const float* x_ln1g = (const float*)d_in[29]; const float* x_ln1b = (const float*)d_in[30];
  const float* h_kW = (const float*)d_in[31];  const float* h_kb = (const float*)d_in[32];
  const float* h_vW = (const float*)d_in[33];  const float* h_vb = (const float*)d_in[34];
  const float* h_oW = (const float*)d_in[35];  const float* h_ob = (const float*)d_in[36];
  const float* h_gam = (const float*)d_in[37];
  const float* h_ln1g = (const float*)d_in[38]; const float* h_ln1b = (const float*)d_in[39];
  const float* h_f1W = (const float*)d_in[40]; const float* h_f1b = (const float*)d_in[41];
  const float* h_f2W = (const float*)d_in[42]; const float* h_f2b = (const float*)d_in[43];
  const float* h_ln2g = (const float*)d_in[44]; const float* h_ln2b = (const float*)d_in[45];
  const float* oln1g = (const float*)d_in[46]; const float* oln1b = (const float*)d_in[47];
  const float* o1W = (const float*)d_in[48];   const float* o1b = (const float*)d_in[49];
  const float* oln2g = (const float*)d_in[50]; const float* oln2b = (const float*)d_in[51];
  const float* o2W = (const float*)d_in[52];   const float* o2b = (const float*)d_in[53];
  const float* oln3g = (const float*)d_in[54]; const float* oln3b = (const float*)d_in[55];
  const float* o3W = (const float*)d_in[56];   const float* o3b = (const float*)d_in[57];

  float* out_f = (float*)d_out;

  const int B = 8, S = 1024, M = B * S;
  const int R = 4097, KQ = 1025, KQP = 1088;   // pad to multiple of 64

  float* ws = (float*)d_ws;
  size_t off = 0;
  auto alloc = [&](size_t nfloats) { size_t o = off; off += (nfloats + 255) & ~(size_t)255; return o; };
  auto allocs = [&](size_t nshorts) { return alloc((nshorts + 1) / 2); };

  size_t oE    = alloc((size_t)R * 256);
  size_t oSIGb = allocs((size_t)R * KQP);
  size_t oSSUM = alloc(R);
  size_t oQE   = alloc((size_t)M * 256);
  size_t oQEb  = allocs((size_t)M * 256);
  size_t oQA   = alloc((size_t)M * 512);
  size_t oQAb  = allocs((size_t)M * 512);
  size_t oYOb  = allocs((size_t)M * 512);
  size_t oXO   = alloc((size_t)M * 256);
  size_t oXOb  = allocs((size_t)M * 256);
  size_t oHO   = alloc((size_t)M * 256);
  size_t oS0   = alloc((size_t)M * 512);   // FFb arena (S0+S1)
  size_t oS1   = alloc((size_t)M * 512);
  size_t oS2b  = allocs((size_t)M * 512);
  size_t oS3   = alloc((size_t)M * 512);
  size_t oS4   = alloc((size_t)M * 512);
  size_t oSX   = alloc((size_t)M * 512);
  size_t oSXb  = allocs((size_t)M * 512);
  size_t oS0b  = allocs((size_t)M * 512);
  size_t oVt   = allocs((size_t)M * 512);
  size_t oWqe  = allocs((size_t)256 * KQP);
  size_t oWyk  = allocs((size_t)512 * 512);
  size_t oWyv  = allocs((size_t)512 * 512);
  size_t oWyo  = allocs((size_t)512 * 512);
  size_t oWyf1 = allocs((size_t)2048 * 512);
  size_t oWyf2 = allocs((size_t)512 * 2048);
  size_t oWxk  = allocs((size_t)256 * 256);
  size_t oWxv  = allocs((size_t)256 * 256);
  size_t oWxo  = allocs((size_t)256 * 256);
  size_t oWhk  = allocs((size_t)256 * 256);
  size_t oWhv  = allocs((size_t)512 * 512);
  size_t oWho  = allocs((size_t)256 * 512);
  size_t oWhf1 = allocs((size_t)2048 * 256);
  size_t oWhf2 = allocs((size_t)256 * 2048);
  size_t oWo1  = allocs((size_t)512 * 512);
  size_t oWo2  = allocs((size_t)256 * 512);
  (void)ws_size; (void)in_sizes; (void)n_in; (void)out_size;

  float* E    = ws + oE;
  unsigned short* SIGb = (unsigned short*)(ws + oSIGb);
  float* SSUM = ws + oSSUM;
  float* QE   = ws + oQE;   unsigned short* QEb = (unsigned short*)(ws + oQEb);
  float* QA   = ws + oQA;   unsigned short* QAb = (unsigned short*)(ws + oQAb);
  unsigned short* YOb = (unsigned short*)(ws + oYOb);
  float* XO   = ws + oXO;   unsigned short* XOb = (unsigned short*)(ws + oXOb);
  float* HO   = ws + oHO;
  float* S0   = ws + oS0;
  unsigned short* S2b = (unsigned short*)(ws + oS2b);
  float* S3   = ws + oS3;
  float* S4   = ws + oS4;
  float* SX   = ws + oSX;   unsigned short* SXb = (unsigned short*)(ws + oSXb);
  unsigned short* S0b = (unsigned short*)(ws + oS0b);
  unsigned short* Vt  = (unsigned short*)(ws + oVt);
  unsigned short* FFb = (unsigned short*)S0;

  unsigned short* Wqe  = (unsigned short*)(ws + oWqe);
  unsigned short* Wyk  = (unsigned short*)(ws + oWyk);
  unsigned short* Wyv  = (unsigned short*)(ws + oWyv);
  unsigned short* Wyo  = (unsigned short*)(ws + oWyo);
  unsigned short* Wyf1 = (unsigned short*)(ws + oWyf1);
  unsigned short* Wyf2 = (unsigned short*)(ws + oWyf2);
  unsigned short* Wxk  = (unsigned short*)(ws + oWxk);
  unsigned short* Wxv  = (unsigned short*)(ws + oWxv);
  unsigned short* Wxo  = (unsigned short*)(ws + oWxo);
  unsigned short* Whk  = (unsigned short*)(ws + oWhk);
  unsigned short* Whv  = (unsigned short*)(ws + oWhv);
  unsigned short* Who  = (unsigned short*)(ws + oWho);
  unsigned short* Whf1 = (unsigned short*)(ws + oWhf1);
  unsigned short* Whf2 = (unsigned short*)(ws + oWhf2);
  unsigned short* Wo1  = (unsigned short*)(ws + oWo1);
  unsigned short* Wo2  = (unsigned short*)(ws + oWo2);

  dim3 blk(256);
  int nElem512 = (8192 * 512 + 255) / 256;

  // ---- fused weight transposes ----
  {
    struct HD { const float* src; unsigned short* dst; int K, N, Kp; };
    const HD hd[16] = {
      {qemb_W, Wqe, KQ, 256, KQP},
      {y_kW, Wyk, 512, 512, 512}, {y_vW, Wyv, 512, 512, 512}, {y_oW, Wyo, 512, 512, 512},
      {y_f1W, Wyf1, 512, 2048, 512}, {y_f2W, Wyf2, 2048, 512, 2048},
      {x_kW, Wxk, 256, 256, 256}, {x_vW, Wxv, 256, 256, 256}, {x_oW, Wxo, 256, 256, 256},
      {h_kW, Whk, 256, 256, 256}, {h_vW, Whv, 512, 512, 512}, {h_oW, Who, 512, 256, 512},
      {h_f1W, Whf1, 256, 2048, 256}, {h_f2W, Whf2, 2048, 256, 2048},
      {o1W, Wo1, 512, 512, 512}, {o2W, Wo2, 512, 256, 512},
    };
    TPack P;
    int tot = 0;
    for (int k = 0; k < 16; ++k) {
      int tx = (hd[k].N + 31) / 32, ty = (hd[k].Kp + 31) / 32;
      P.d[k] = { hd[k].src, hd[k].dst, hd[k].K, hd[k].N, hd[k].Kp, tx, tot };
      tot += tx * ty;
    }
    tconv_all_kernel<<<dim3(tot), blk, 0, stream>>>(P);
  }

  auto gg = [](int BMv, int TNv, int Mm, int Nn) {
    return dim3((unsigned)(Nn / TNv), (unsigned)((Mm + BMv - 1) / BMv));
  };

  // 1. embedding table
  sig_kernel<<<R, blk, 0, stream>>>(pemb_W, SIGb, SSUM, KQ, KQP);
  mgemm_kernel<64, 64, 2, true, false, false><<<gg(64, 64, R, 256), blk, 0, stream>>>(SIGb, Wqe, qemb_b, E, nullptr, nullptr, R, 256, KQP, SSUM, nullptr, 0);
  gather_kernel<<<nElem512, blk, 0, stream>>>(p_data, pa_data, E, diff_W, QE, QEb, QA, QAb);
  creg_kernel<<<1, blk, 0, stream>>>(p_data, diff_W, out_f + 8192);

  dim3 ablk(512);
  dim3 lgrid(M / 4);
  dim3 agA(64, B * NHEADS);

  // 2. y layer (dm=512, mask_k=1, zero_pad=0, FFN). Fused KV proj.
  mgemm_kernel<128, 64, 0, false, true, true><<<gg(128, 64, M, 1024), blk, 0, stream>>>(QAb, Wyk, y_kb, nullptr, S0b, Vt, M, 1024, 512, nullptr, y_vb, 512);
  attnC_kernel<64, 64, 1, 0><<<agA, ablk, 0, stream>>>(S0b, Vt, y_gam, S2b, S, M);
  mgemm_kernel<128, 64, 0, true, false, false><<<gg(128, 64, M, 512), blk, 0, stream>>>(S2b, Wyo, y_ob, S3, nullptr, nullptr, M, 512, 512, nullptr, nullptr, 0);
  ln4_kernel<512, true, true><<<lgrid, blk, 0, stream>>>(QA, S3, y_ln1g, y_ln1b, SX, SXb);
  mgemm_kernel<128, 128, 1, false, true, false><<<gg(128, 128, M, 2048), blk, 0, stream>>>(SXb, Wyf1, y_f1b, nullptr, FFb, nullptr, M, 2048, 512, nullptr, nullptr, 0);
  mgemm_kernel<128, 64, 0, true, false, false><<<gg(128, 64, M, 512), blk, 0, stream>>>(FFb, Wyf2, y_f2b, S4, nullptr, nullptr, M, 512, 2048, nullptr, nullptr, 0);
  ln4_kernel<512, false, true><<<lgrid, blk, 0, stream>>>(SX, S4, y_ln2g, y_ln2b, nullptr, YOb);

  // 3. x layer (dm=256, mask_k=1, zero_pad=0, no FFN). Fused KV proj.
  mgemm_kernel<128, 64, 0, false, true, true><<<gg(128, 64, M, 512), blk, 0, stream>>>(QEb, Wxk, x_kb, nullptr, S0b, Vt, M, 512, 256, nullptr, x_vb, 256);
  attnC_kernel<32, 32, 1, 0><<<agA, ablk, 0, stream>>>(S0b, Vt, x_gam, S2b, S, M);
  mgemm_kernel<64, 64, 0, true, false, false><<<gg(64, 64, M, 256), blk, 0, stream>>>(S2b, Wxo, x_ob, S3, nullptr, nullptr, M, 256, 256, nullptr, nullptr, 0);
  ln4_kernel<256, true, true><<<lgrid, blk, 0, stream>>>(QE, S3, x_ln1g, x_ln1b, XO, XOb);

  // 4. h layer (q,k from XO; v from YO; mask_k=0, zero_pad=1, FFN)
  mgemm_kernel<64, 64, 0, false, true, false><<<gg(64, 64, M, 256), blk, 0, stream>>>(XOb, Whk, h_kb, nullptr, S0b, nullptr, M, 256, 256, nullptr, nullptr, 0);
  mgemm_kernel<128, 64, 0, false, false, true><<<gg(128, 64, M, 512), blk, 0, stream>>>(YOb, Whv, h_vb, nullptr, nullptr, Vt, M, 512, 512, nullptr, nullptr, 0);
  attnC_kernel<32, 64, 0, 1><<<agA, ablk, 0, stream>>>(S0b, Vt, h_gam, S2b, S, M);
  mgemm_kernel<64, 64, 0, true, false, false><<<gg(64, 64, M, 256), blk, 0, stream>>>(S2b, Who, h_ob, S3, nullptr, nullptr, M, 256, 512, nullptr, nullptr, 0);
  ln4_kernel<256, true, true><<<lgrid, blk, 0, stream>>>(XO, S3, h_ln1g, h_ln1b, SX, SXb);
  mgemm_kernel<128, 128, 1, false, true, false><<<gg(128, 128, M, 2048), blk, 0, stream>>>(SXb, Whf1, h_f1b, nullptr, FFb, nullptr, M, 2048, 256, nullptr, nullptr, 0);
  mgemm_kernel<64, 64, 0, true, false, false><<<gg(64, 64, M, 256), blk, 0, stream>>>(FFb, Whf2, h_f2b, S4, nullptr, nullptr, M, 256, 2048, nullptr, nullptr, 0);
  ln4_kernel<256, true, false><<<lgrid, blk, 0, stream>>>(SX, S4, h_ln2g, h_ln2b, HO, nullptr);

  // 5. head: LN(concat) -> o1 -> LN -> o2 -> LN+dot
  lnc_kernel<<<lgrid, blk, 0, stream>>>(HO, QE, oln1g, oln1b, SXb);
  mgemm_kernel<128, 64, 1, true, false, false><<<gg(128, 64, M, 512), blk, 0, stream>>>(SXb, Wo1, o1b, S3, nullptr, nullptr, M, 512, 512, nullptr, nullptr, 0);
  ln4_kernel<512, false, true><<<lgrid, blk, 0, stream>>>(S3, nullptr, oln2g, oln2b, nullptr, SXb);
  mgemm_kernel<64, 64, 1, true, false, false><<<gg(64, 64, M, 256), blk, 0, stream>>>(SXb, Wo2, o2b, S4, nullptr, nullptr, M, 256, 512, nullptr, nullptr, 0);
  lndot_kernel<<<lgrid, blk, 0, stream>>>(S4, oln3g, oln3b, o3W, o3b, out_f);
}